// Round 1
// baseline (211.803 us; speedup 1.0000x reference)
//
#include <hip/hip_runtime.h>
#include <cstdint>

// FlashAttention fused block: q/k/v proj -> causal attn -> out proj
// B=2, N=2048, DIM=1024, H=16, Dh=64. All compute bf16 MFMA + fp32 accum.

typedef __bf16 bf16_t;
typedef __bf16 bf16x8 __attribute__((ext_vector_type(8)));
typedef __bf16 bf16x4 __attribute__((ext_vector_type(4)));
typedef float  f32x4  __attribute__((ext_vector_type(4)));

#define LOG2E 1.44269504088896340736f

// global -> LDS direct DMA, 16B per lane. LDS dest must be uniform-base + lane*16.
__device__ __forceinline__ void gload_lds16(const void* gsrc, void* ldst) {
  __builtin_amdgcn_global_load_lds(
      (__attribute__((address_space(1))) void*)(uintptr_t)gsrc,
      (__attribute__((address_space(3))) void*)(uintptr_t)(uint32_t)(uintptr_t)ldst,
      16, 0, 0);
}

// ---------------- prep: fp32 -> bf16 convert ----------------
__global__ __launch_bounds__(256) void cvt_kernel(const float* __restrict__ in,
                                                  bf16_t* __restrict__ out) {
  const int idx = (blockIdx.x * 256 + threadIdx.x) * 4;
  const float4 v = *(const float4*)(in + idx);
  bf16x4 o;
  o[0] = (bf16_t)v.x; o[1] = (bf16_t)v.y; o[2] = (bf16_t)v.z; o[3] = (bf16_t)v.w;
  *(bf16x4*)(out + idx) = o;
}

// ---------------- prep: W [K][Nn] fp32 -> Wt [Nn][K] bf16 ----------------
__global__ __launch_bounds__(256) void transpose_kernel(const float* __restrict__ W,
                                                        bf16_t* __restrict__ Wt,
                                                        int K, int Nn) {
  __shared__ float tile[32][33];
  const int bx = blockIdx.x, by = blockIdx.y;
  const int x = bx * 32 + threadIdx.x;
  #pragma unroll
  for (int r0 = 0; r0 < 32; r0 += 8) {
    const int r = r0 + threadIdx.y;
    tile[r][threadIdx.x] = W[(size_t)(by * 32 + r) * Nn + x];
  }
  __syncthreads();
  const int xo = by * 32 + threadIdx.x;
  #pragma unroll
  for (int r0 = 0; r0 < 32; r0 += 8) {
    const int r = r0 + threadIdx.y;
    Wt[(size_t)(bx * 32 + r) * K + xo] = (bf16_t)tile[threadIdx.x][r];
  }
}

// ---------------- GEMM: C[M][Nn] = A[M][1024] @ Bt[Nn][1024]^T ----------------
// 128x128 tile, BK=64, 4 waves (2x2 of 64x64), 16x16x32 bf16 MFMA.
// LDS chunk swizzle: physical chunk c holds logical chunk c ^ (row&7).
// MODE 0: out0 = Q bf16 [bh][n][64]
// MODE 1: ci<1024 -> out0 = K bf16 [bh][n][64]; ci>=1024 -> out1 = V^T bf16 [bh][64][n]
// MODE 2: outf = fp32 row-major [M][1024]
template <int MODE>
__global__ __launch_bounds__(256) void gemm_kernel(
    const bf16_t* __restrict__ A, const bf16_t* __restrict__ Bt,
    bf16_t* __restrict__ out0, bf16_t* __restrict__ out1,
    float* __restrict__ outf) {
  constexpr int KD = 1024;
  __shared__ bf16_t As[128][64];
  __shared__ bf16_t Bs[128][64];
  const int t = threadIdx.x;
  const int lane = t & 63, w = t >> 6;
  const int wr = w >> 1, wc = w & 1;
  const int lrow = lane & 15, lq = lane >> 4;
  const int bm = blockIdx.y * 128, bn = blockIdx.x * 128;

  f32x4 acc[4][4] = {};

  for (int kt = 0; kt < KD / 64; ++kt) {
    const int k0 = kt * 64;
    #pragma unroll
    for (int i = 0; i < 4; ++i) {  // 128 rows x 8 chunks = 1024 chunks / 256 thr
      const int lin = i * 256 + t;
      const int row = lin >> 3;
      const int sc = (lin & 7) ^ (row & 7);  // pre-swizzled global source chunk
      gload_lds16(A + (size_t)(bm + row) * KD + k0 + sc * 8, &As[0][0] + lin * 8);
      gload_lds16(Bt + (size_t)(bn + row) * KD + k0 + sc * 8, &Bs[0][0] + lin * 8);
    }
    __syncthreads();
    #pragma unroll
    for (int kk = 0; kk < 2; ++kk) {
      bf16x8 aF[4], bF[4];
      #pragma unroll
      for (int m = 0; m < 4; ++m) {
        const int row = wr * 64 + m * 16 + lrow;
        const int ch = (kk * 4 + lq) ^ (row & 7);
        aF[m] = *(const bf16x8*)&As[row][ch * 8];
      }
      #pragma unroll
      for (int n = 0; n < 4; ++n) {
        const int row = wc * 64 + n * 16 + lrow;
        const int ch = (kk * 4 + lq) ^ (row & 7);
        bF[n] = *(const bf16x8*)&Bs[row][ch * 8];
      }
      #pragma unroll
      for (int m = 0; m < 4; ++m)
        #pragma unroll
        for (int n = 0; n < 4; ++n)
          acc[m][n] = __builtin_amdgcn_mfma_f32_16x16x32_bf16(aF[m], bF[n],
                                                              acc[m][n], 0, 0, 0);
    }
    __syncthreads();
  }

  // epilogue. D layout: row = lq*4 + r, col = lrow (verified m89/m91)
  #pragma unroll
  for (int m = 0; m < 4; ++m) {
    const int ri = bm + wr * 64 + m * 16 + lq * 4;
    #pragma unroll
    for (int n = 0; n < 4; ++n) {
      const int ci = bn + wc * 64 + n * 16 + lrow;
      const f32x4 v = acc[m][n];
      if (MODE == 2) {
        #pragma unroll
        for (int r = 0; r < 4; ++r)
          outf[(size_t)(ri + r) * 1024 + ci] = v[r];
      } else {
        if (MODE == 0 || ci < 1024) {
          const int h = (ci & 1023) >> 6, d = ci & 63;
          #pragma unroll
          for (int r = 0; r < 4; ++r) {
            const int i = ri + r;
            const int b = i >> 11, ii = i & 2047;
            out0[(((size_t)(b * 16 + h) * 2048 + ii) << 6) + d] = (bf16_t)v[r];
          }
        } else {
          const int hd = ci - 1024;
          const int h = hd >> 6, d = hd & 63;
          const int b = ri >> 11, ii = ri & 2047;  // 4 consecutive rows, same b
          bf16x4 pk;
          pk[0] = (bf16_t)v[0]; pk[1] = (bf16_t)v[1];
          pk[2] = (bf16_t)v[2]; pk[3] = (bf16_t)v[3];
          *(bf16x4*)(out1 + (((size_t)(b * 16 + h) * 64 + d) << 11) + ii) = pk;
        }
      }
    }
  }
}

// ---------------- flash attention ----------------
// grid: (32 qtiles, 32 bh). 4 waves x 16 q-rows; KV tiles of 64; causal.
// Q [bh][n][64], K [bh][n][64], Vt [bh][64][n], all bf16. Out attn [b][n][1024] bf16.
__global__ __launch_bounds__(256) void attn_kernel(
    const bf16_t* __restrict__ Qw, const bf16_t* __restrict__ Kw,
    const bf16_t* __restrict__ Vtw, bf16_t* __restrict__ Ow) {
  __shared__ bf16_t Ks[64][64];
  __shared__ bf16_t Vs[64][64];       // logical [d][j]
  __shared__ bf16_t Ps[4][16][72];    // per-wave P re-layout (padded stride)
  const int t = threadIdx.x;
  const int lane = t & 63, w = t >> 6;
  const int lrow = lane & 15, lq = lane >> 4;
  const int bh = blockIdx.y;
  const int qt = gridDim.x - 1 - blockIdx.x;  // longest blocks dispatch first
  const int q0 = qt * 64;
  const bf16_t* Qb = Qw + (size_t)bh * 2048 * 64;
  const bf16_t* Kb = Kw + (size_t)bh * 2048 * 64;
  const bf16_t* Vb = Vtw + (size_t)bh * 64 * 2048;

  // hoist Q fragments: A-operand layout r=lane&15, k=(lane>>4)*8+b
  bf16x8 qf[2];
  #pragma unroll
  for (int kk = 0; kk < 2; ++kk)
    qf[kk] = *(const bf16x8*)(Qb + (size_t)(q0 + w * 16 + lrow) * 64 + kk * 32 + lq * 8);

  f32x4 acc_o[4] = {};
  float mrun[4], lrun[4];
  #pragma unroll
  for (int r = 0; r < 4; ++r) { mrun[r] = -1e30f; lrun[r] = 0.f; }

  const int ntiles = qt + 1;
  for (int jt = 0; jt < ntiles; ++jt) {
    const int jb = jt * 64;
    #pragma unroll
    for (int i = 0; i < 2; ++i) {  // 64 rows x 8 chunks = 512 chunks / 256 thr
      const int lin = i * 256 + t;
      const int row = lin >> 3;
      const int sc = (lin & 7) ^ (row & 7);
      gload_lds16(Kb + (size_t)(jb + row) * 64 + sc * 8, &Ks[0][0] + lin * 8);
      gload_lds16(Vb + (size_t)row * 2048 + jb + sc * 8, &Vs[0][0] + lin * 8);
    }
    __syncthreads();

    // S = Q K^T  (D: row = q = lq*4+r, col = j = j4*16+lrow)
    f32x4 s[4] = {};
    #pragma unroll
    for (int j4 = 0; j4 < 4; ++j4) {
      const int row = j4 * 16 + lrow;
      #pragma unroll
      for (int kk = 0; kk < 2; ++kk) {
        const int ch = (kk * 4 + lq) ^ (row & 7);
        const bf16x8 kf = *(const bf16x8*)&Ks[row][ch * 8];
        s[j4] = __builtin_amdgcn_mfma_f32_16x16x32_bf16(qf[kk], kf, s[j4], 0, 0, 0);
      }
    }

    // scale + causal mask + row-max (rows live in 16-lane groups)
    float p[4][4], mx[4];
    #pragma unroll
    for (int r = 0; r < 4; ++r) mx[r] = -1e30f;
    const bool diag = (jb == q0);
    #pragma unroll
    for (int j4 = 0; j4 < 4; ++j4) {
      #pragma unroll
      for (int r = 0; r < 4; ++r) {
        float sv = s[j4][r] * 0.125f;
        if (diag && (jb + j4 * 16 + lrow > q0 + w * 16 + lq * 4 + r)) sv = -1e30f;
        p[j4][r] = sv;
        mx[r] = fmaxf(mx[r], sv);
      }
    }
    #pragma unroll
    for (int r = 0; r < 4; ++r) {
      #pragma unroll
      for (int off = 1; off < 16; off <<= 1)
        mx[r] = fmaxf(mx[r], __shfl_xor(mx[r], off, 64));
      const float mnew = fmaxf(mrun[r], mx[r]);
      const float corr = exp2f((mrun[r] - mnew) * LOG2E);
      mrun[r] = mnew;
      lrun[r] *= corr;
      #pragma unroll
      for (int d4 = 0; d4 < 4; ++d4) acc_o[d4][r] *= corr;
    }
    float rs[4] = {0.f, 0.f, 0.f, 0.f};
    #pragma unroll
    for (int j4 = 0; j4 < 4; ++j4)
      #pragma unroll
      for (int r = 0; r < 4; ++r) {
        const float pv = exp2f((p[j4][r] - mrun[r]) * LOG2E);
        p[j4][r] = pv;
        rs[r] += pv;
      }
    #pragma unroll
    for (int r = 0; r < 4; ++r) {
      #pragma unroll
      for (int off = 1; off < 16; off <<= 1)
        rs[r] += __shfl_xor(rs[r], off, 64);
      lrun[r] += rs[r];
    }

    // P: C/D layout -> A layout via per-wave LDS round-trip (same-wave DS order)
    #pragma unroll
    for (int j4 = 0; j4 < 4; ++j4)
      #pragma unroll
      for (int r = 0; r < 4; ++r)
        Ps[w][lq * 4 + r][j4 * 16 + lrow] = (bf16_t)p[j4][r];

    #pragma unroll
    for (int kk = 0; kk < 2; ++kk) {
      const bf16x8 pa = *(const bf16x8*)&Ps[w][lrow][kk * 32 + lq * 8];
      #pragma unroll
      for (int d4 = 0; d4 < 4; ++d4) {
        const int row = d4 * 16 + lrow;
        const int ch = (kk * 4 + lq) ^ (row & 7);
        const bf16x8 vf = *(const bf16x8*)&Vs[row][ch * 8];
        acc_o[d4] = __builtin_amdgcn_mfma_f32_16x16x32_bf16(pa, vf, acc_o[d4], 0, 0, 0);
      }
    }
    __syncthreads();
  }

  const int b = bh >> 4, h = bh & 15;
  #pragma unroll
  for (int r = 0; r < 4; ++r) {
    const float inv = 1.0f / lrun[r];
    const int ig = q0 + w * 16 + lq * 4 + r;
    const size_t base = ((size_t)(b * 2048 + ig) << 10) + h * 64;
    #pragma unroll
    for (int d4 = 0; d4 < 4; ++d4)
      Ow[base + d4 * 16 + lrow] = (bf16_t)(acc_o[d4][r] * inv);
  }
}

// ---------------- orchestration ----------------
extern "C" void kernel_launch(void* const* d_in, const int* in_sizes, int n_in,
                              void* d_out, int out_size, void* d_ws, size_t ws_size,
                              hipStream_t stream) {
  const float* x   = (const float*)d_in[0];
  const float* Wq  = (const float*)d_in[1];
  const float* Wkv = (const float*)d_in[2];
  const float* Wo  = (const float*)d_in[3];
  float* out = (float*)d_out;
  char* ws = (char*)d_ws;

  const size_t MB = 1024 * 1024;
  bf16_t* Xbf  = (bf16_t*)(ws);             // [4096][1024]       8 MiB
  bf16_t* Wqt  = (bf16_t*)(ws + 8 * MB);    // [1024][1024]       2 MiB
  bf16_t* Wkvt = (bf16_t*)(ws + 10 * MB);   // [2048][1024]       4 MiB
  bf16_t* Wot  = (bf16_t*)(ws + 14 * MB);   // [1024][1024]       2 MiB
  bf16_t* Qw   = (bf16_t*)(ws + 16 * MB);   // [32][2048][64]     8 MiB
  bf16_t* Kw   = (bf16_t*)(ws + 24 * MB);   // [32][2048][64]     8 MiB
  bf16_t* Vtw  = (bf16_t*)(ws + 32 * MB);   // [32][64][2048]     8 MiB
  bf16_t* Aw   = (bf16_t*)(ws + 40 * MB);   // [4096][1024]       8 MiB

  cvt_kernel<<<4096, 256, 0, stream>>>(x, Xbf);
  dim3 tb(32, 8);
  transpose_kernel<<<dim3(32, 32), tb, 0, stream>>>(Wq, Wqt, 1024, 1024);
  transpose_kernel<<<dim3(64, 32), tb, 0, stream>>>(Wkv, Wkvt, 1024, 2048);
  transpose_kernel<<<dim3(32, 32), tb, 0, stream>>>(Wo, Wot, 1024, 1024);

  gemm_kernel<0><<<dim3(8, 32), 256, 0, stream>>>(Xbf, Wqt, Qw, nullptr, nullptr);
  gemm_kernel<1><<<dim3(16, 32), 256, 0, stream>>>(Xbf, Wkvt, Kw, Vtw, nullptr);
  attn_kernel<<<dim3(32, 32), 256, 0, stream>>>(Qw, Kw, Vtw, Aw);
  gemm_kernel<2><<<dim3(8, 32), 256, 0, stream>>>(Aw, Wot, nullptr, nullptr, out);
}

// Round 2
// 206.698 us; speedup vs baseline: 1.0247x; 1.0247x over previous
//
#include <hip/hip_runtime.h>
#include <cstdint>

// FlashAttention fused block: q/k/v proj -> causal attn -> out proj
// B=2, N=2048, DIM=1024, H=16, Dh=64. All compute bf16 MFMA + fp32 accum.
// R2: 2-phase double-buffer prefetch (counted vmcnt) in attn + GEMM; Q pre-scaled.

typedef __bf16 bf16_t;
typedef __bf16 bf16x8 __attribute__((ext_vector_type(8)));
typedef __bf16 bf16x4 __attribute__((ext_vector_type(4)));
typedef float  f32x4  __attribute__((ext_vector_type(4)));

#define LOG2E 1.44269504088896340736f
#define QSCALE 0.18033688011112042f  /* 0.125 * log2(e) */

// global -> LDS direct DMA, 16B per lane. LDS dest must be uniform-base + lane*16.
__device__ __forceinline__ void gload_lds16(const void* gsrc, void* ldst) {
  __builtin_amdgcn_global_load_lds(
      (__attribute__((address_space(1))) void*)(uintptr_t)gsrc,
      (__attribute__((address_space(3))) void*)(uintptr_t)(uint32_t)(uintptr_t)ldst,
      16, 0, 0);
}

// ---------------- prep: fp32 -> bf16 convert ----------------
__global__ __launch_bounds__(256) void cvt_kernel(const float* __restrict__ in,
                                                  bf16_t* __restrict__ out) {
  const int idx = (blockIdx.x * 256 + threadIdx.x) * 4;
  const float4 v = *(const float4*)(in + idx);
  bf16x4 o;
  o[0] = (bf16_t)v.x; o[1] = (bf16_t)v.y; o[2] = (bf16_t)v.z; o[3] = (bf16_t)v.w;
  *(bf16x4*)(out + idx) = o;
}

// ---------------- prep: W [K][Nn] fp32 -> Wt [Nn][K] bf16 ----------------
__global__ __launch_bounds__(256) void transpose_kernel(const float* __restrict__ W,
                                                        bf16_t* __restrict__ Wt,
                                                        int K, int Nn) {
  __shared__ float tile[32][33];
  const int bx = blockIdx.x, by = blockIdx.y;
  const int x = bx * 32 + threadIdx.x;
  #pragma unroll
  for (int r0 = 0; r0 < 32; r0 += 8) {
    const int r = r0 + threadIdx.y;
    tile[r][threadIdx.x] = W[(size_t)(by * 32 + r) * Nn + x];
  }
  __syncthreads();
  const int xo = by * 32 + threadIdx.x;
  #pragma unroll
  for (int r0 = 0; r0 < 32; r0 += 8) {
    const int r = r0 + threadIdx.y;
    Wt[(size_t)(bx * 32 + r) * K + xo] = (bf16_t)tile[threadIdx.x][r];
  }
}

// ---------------- GEMM: C[M][Nn] = A[M][1024] @ Bt[Nn][1024]^T ----------------
// 128x128 tile, BK=64, 4 waves (2x2 of 64x64), 16x16x32 bf16 MFMA.
// LDS chunk swizzle: physical chunk c holds logical chunk c ^ (row&7).
// 2-phase double-buffer: prefetch next K-tile, counted vmcnt(8).
// MODE 0: out0 = Q bf16 [bh][n][64], pre-scaled by 0.125*log2e
// MODE 1: ci<1024 -> out0 = K bf16 [bh][n][64]; ci>=1024 -> out1 = V^T bf16 [bh][64][n]
// MODE 2: outf = fp32 row-major [M][1024]
template <int MODE>
__global__ __launch_bounds__(256) void gemm_kernel(
    const bf16_t* __restrict__ A, const bf16_t* __restrict__ Bt,
    bf16_t* __restrict__ out0, bf16_t* __restrict__ out1,
    float* __restrict__ outf) {
  constexpr int KD = 1024;
  __shared__ bf16_t As[2][128][64];
  __shared__ bf16_t Bs[2][128][64];
  const int t = threadIdx.x;
  const int lane = t & 63, w = t >> 6;
  const int wr = w >> 1, wc = w & 1;
  const int lrow = lane & 15, lq = lane >> 4;
  const int bm = blockIdx.y * 128, bn = blockIdx.x * 128;

  f32x4 acc[4][4] = {};

  // stage K-tile kt into buffer buf (8 gload_lds per thread)
  auto stage = [&](int buf, int k0) {
    #pragma unroll
    for (int i = 0; i < 4; ++i) {  // 128 rows x 8 chunks = 1024 chunks / 256 thr
      const int lin = i * 256 + t;
      const int row = lin >> 3;
      const int sc = (lin & 7) ^ (row & 7);  // pre-swizzled global source chunk
      gload_lds16(A + (size_t)(bm + row) * KD + k0 + sc * 8,
                  &As[buf][0][0] + lin * 8);
      gload_lds16(Bt + (size_t)(bn + row) * KD + k0 + sc * 8,
                  &Bs[buf][0][0] + lin * 8);
    }
  };

  stage(0, 0);
  for (int kt = 0; kt < KD / 64; ++kt) {
    const int cur = kt & 1;
    if (kt + 1 < KD / 64) {
      stage(cur ^ 1, (kt + 1) * 64);
      asm volatile("s_waitcnt vmcnt(8)" ::: "memory");
    } else {
      asm volatile("s_waitcnt vmcnt(0)" ::: "memory");
    }
    __builtin_amdgcn_s_barrier();

    #pragma unroll
    for (int kk = 0; kk < 2; ++kk) {
      bf16x8 aF[4], bF[4];
      #pragma unroll
      for (int m = 0; m < 4; ++m) {
        const int row = wr * 64 + m * 16 + lrow;
        const int ch = (kk * 4 + lq) ^ (row & 7);
        aF[m] = *(const bf16x8*)&As[cur][row][ch * 8];
      }
      #pragma unroll
      for (int n = 0; n < 4; ++n) {
        const int row = wc * 64 + n * 16 + lrow;
        const int ch = (kk * 4 + lq) ^ (row & 7);
        bF[n] = *(const bf16x8*)&Bs[cur][row][ch * 8];
      }
      #pragma unroll
      for (int m = 0; m < 4; ++m)
        #pragma unroll
        for (int n = 0; n < 4; ++n)
          acc[m][n] = __builtin_amdgcn_mfma_f32_16x16x32_bf16(aF[m], bF[n],
                                                              acc[m][n], 0, 0, 0);
    }
    asm volatile("s_waitcnt lgkmcnt(0)" ::: "memory");
    __builtin_amdgcn_s_barrier();
  }

  // epilogue. D layout: row = lq*4 + r, col = lrow (verified m89/m91)
  #pragma unroll
  for (int m = 0; m < 4; ++m) {
    const int ri = bm + wr * 64 + m * 16 + lq * 4;
    #pragma unroll
    for (int n = 0; n < 4; ++n) {
      const int ci = bn + wc * 64 + n * 16 + lrow;
      const f32x4 v = acc[m][n];
      if (MODE == 2) {
        #pragma unroll
        for (int r = 0; r < 4; ++r)
          outf[(size_t)(ri + r) * 1024 + ci] = v[r];
      } else {
        if (MODE == 0 || ci < 1024) {
          const int h = (ci & 1023) >> 6, d = ci & 63;
          const float sc = (MODE == 0) ? QSCALE : 1.0f;
          #pragma unroll
          for (int r = 0; r < 4; ++r) {
            const int i = ri + r;
            const int b = i >> 11, ii = i & 2047;
            out0[(((size_t)(b * 16 + h) * 2048 + ii) << 6) + d] = (bf16_t)(v[r] * sc);
          }
        } else {
          const int hd = ci - 1024;
          const int h = hd >> 6, d = hd & 63;
          const int b = ri >> 11, ii = ri & 2047;  // 4 consecutive rows, same b
          bf16x4 pk;
          pk[0] = (bf16_t)v[0]; pk[1] = (bf16_t)v[1];
          pk[2] = (bf16_t)v[2]; pk[3] = (bf16_t)v[3];
          *(bf16x4*)(out1 + (((size_t)(b * 16 + h) * 64 + d) << 11) + ii) = pk;
        }
      }
    }
  }
}

// ---------------- flash attention ----------------
// grid: (32 qtiles, 32 bh). 4 waves x 16 q-rows; KV tiles of 64; causal.
// Q pre-scaled by 0.125*log2e -> softmax uses exp2 directly.
// 2-phase double-buffered K/V, counted vmcnt(4) prefetch.
__global__ __launch_bounds__(256) void attn_kernel(
    const bf16_t* __restrict__ Qw, const bf16_t* __restrict__ Kw,
    const bf16_t* __restrict__ Vtw, bf16_t* __restrict__ Ow) {
  __shared__ bf16_t Ks[2][64][64];
  __shared__ bf16_t Vs[2][64][64];    // logical [d][j]
  __shared__ bf16_t Ps[4][16][72];    // per-wave P re-layout (padded stride)
  const int t = threadIdx.x;
  const int lane = t & 63, w = t >> 6;
  const int lrow = lane & 15, lq = lane >> 4;
  const int bh = blockIdx.y;
  const int qt = gridDim.x - 1 - blockIdx.x;  // longest blocks dispatch first
  const int q0 = qt * 64;
  const bf16_t* Qb = Qw + (size_t)bh * 2048 * 64;
  const bf16_t* Kb = Kw + (size_t)bh * 2048 * 64;
  const bf16_t* Vb = Vtw + (size_t)bh * 64 * 2048;

  // hoist Q fragments: A-operand layout r=lane&15, k=(lane>>4)*8+b
  bf16x8 qf[2];
  #pragma unroll
  for (int kk = 0; kk < 2; ++kk)
    qf[kk] = *(const bf16x8*)(Qb + (size_t)(q0 + w * 16 + lrow) * 64 + kk * 32 + lq * 8);

  f32x4 acc_o[4] = {};
  float mrun[4], lrun[4];
  #pragma unroll
  for (int r = 0; r < 4; ++r) { mrun[r] = -1e30f; lrun[r] = 0.f; }

  // stage KV tile at jb into buffer buf (4 gload_lds per thread)
  auto stage = [&](int buf, int jb) {
    #pragma unroll
    for (int i = 0; i < 2; ++i) {  // 64 rows x 8 chunks = 512 chunks / 256 thr
      const int lin = i * 256 + t;
      const int row = lin >> 3;
      const int sc = (lin & 7) ^ (row & 7);
      gload_lds16(Kb + (size_t)(jb + row) * 64 + sc * 8, &Ks[buf][0][0] + lin * 8);
      gload_lds16(Vb + (size_t)row * 2048 + jb + sc * 8, &Vs[buf][0][0] + lin * 8);
    }
  };

  const int ntiles = qt + 1;
  stage(0, 0);
  for (int jt = 0; jt < ntiles; ++jt) {
    const int jb = jt * 64;
    const int cur = jt & 1;
    if (jt + 1 < ntiles) {
      stage(cur ^ 1, jb + 64);
      asm volatile("s_waitcnt vmcnt(4)" ::: "memory");
    } else {
      asm volatile("s_waitcnt vmcnt(0)" ::: "memory");
    }
    __builtin_amdgcn_s_barrier();

    // S = Q K^T  (D: row = q = lq*4+r, col = j = j4*16+lrow); Q pre-scaled
    f32x4 s[4] = {};
    #pragma unroll
    for (int j4 = 0; j4 < 4; ++j4) {
      const int row = j4 * 16 + lrow;
      #pragma unroll
      for (int kk = 0; kk < 2; ++kk) {
        const int ch = (kk * 4 + lq) ^ (row & 7);
        const bf16x8 kf = *(const bf16x8*)&Ks[cur][row][ch * 8];
        s[j4] = __builtin_amdgcn_mfma_f32_16x16x32_bf16(qf[kk], kf, s[j4], 0, 0, 0);
      }
    }

    // causal mask + row-max (rows live in 16-lane groups); values already log2-scaled
    float p[4][4], mx[4];
    #pragma unroll
    for (int r = 0; r < 4; ++r) mx[r] = -1e30f;
    const bool diag = (jb == q0);
    #pragma unroll
    for (int j4 = 0; j4 < 4; ++j4) {
      #pragma unroll
      for (int r = 0; r < 4; ++r) {
        float sv = s[j4][r];
        if (diag && (jb + j4 * 16 + lrow > q0 + w * 16 + lq * 4 + r)) sv = -1e30f;
        p[j4][r] = sv;
        mx[r] = fmaxf(mx[r], sv);
      }
    }
    #pragma unroll
    for (int r = 0; r < 4; ++r) {
      #pragma unroll
      for (int off = 1; off < 16; off <<= 1)
        mx[r] = fmaxf(mx[r], __shfl_xor(mx[r], off, 64));
      const float mnew = fmaxf(mrun[r], mx[r]);
      const float corr = exp2f(mrun[r] - mnew);
      mrun[r] = mnew;
      lrun[r] *= corr;
      #pragma unroll
      for (int d4 = 0; d4 < 4; ++d4) acc_o[d4][r] *= corr;
    }
    float rs[4] = {0.f, 0.f, 0.f, 0.f};
    #pragma unroll
    for (int j4 = 0; j4 < 4; ++j4)
      #pragma unroll
      for (int r = 0; r < 4; ++r) {
        const float pv = exp2f(p[j4][r] - mrun[r]);
        p[j4][r] = pv;
        rs[r] += pv;
      }
    #pragma unroll
    for (int r = 0; r < 4; ++r) {
      #pragma unroll
      for (int off = 1; off < 16; off <<= 1)
        rs[r] += __shfl_xor(rs[r], off, 64);
      lrun[r] += rs[r];
    }

    // P: C/D layout -> A layout via per-wave LDS round-trip (same-wave DS order)
    #pragma unroll
    for (int j4 = 0; j4 < 4; ++j4)
      #pragma unroll
      for (int r = 0; r < 4; ++r)
        Ps[w][lq * 4 + r][j4 * 16 + lrow] = (bf16_t)p[j4][r];

    #pragma unroll
    for (int kk = 0; kk < 2; ++kk) {
      const bf16x8 pa = *(const bf16x8*)&Ps[w][lrow][kk * 32 + lq * 8];
      #pragma unroll
      for (int d4 = 0; d4 < 4; ++d4) {
        const int row = d4 * 16 + lrow;
        const int ch = (kk * 4 + lq) ^ (row & 7);
        const bf16x8 vf = *(const bf16x8*)&Vs[cur][row][ch * 8];
        acc_o[d4] = __builtin_amdgcn_mfma_f32_16x16x32_bf16(pa, vf, acc_o[d4], 0, 0, 0);
      }
    }
    asm volatile("s_waitcnt lgkmcnt(0)" ::: "memory");
    __builtin_amdgcn_s_barrier();
  }

  const int b = bh >> 4, h = bh & 15;
  #pragma unroll
  for (int r = 0; r < 4; ++r) {
    const float inv = 1.0f / lrun[r];
    const int ig = q0 + w * 16 + lq * 4 + r;
    const size_t base = ((size_t)(b * 2048 + ig) << 10) + h * 64;
    #pragma unroll
    for (int d4 = 0; d4 < 4; ++d4)
      Ow[base + d4 * 16 + lrow] = (bf16_t)(acc_o[d4][r] * inv);
  }
}

// ---------------- orchestration ----------------
extern "C" void kernel_launch(void* const* d_in, const int* in_sizes, int n_in,
                              void* d_out, int out_size, void* d_ws, size_t ws_size,
                              hipStream_t stream) {
  const float* x   = (const float*)d_in[0];
  const float* Wq  = (const float*)d_in[1];
  const float* Wkv = (const float*)d_in[2];
  const float* Wo  = (const float*)d_in[3];
  float* out = (float*)d_out;
  char* ws = (char*)d_ws;

  const size_t MB = 1024 * 1024;
  bf16_t* Xbf  = (bf16_t*)(ws);             // [4096][1024]       8 MiB
  bf16_t* Wqt  = (bf16_t*)(ws + 8 * MB);    // [1024][1024]       2 MiB
  bf16_t* Wkvt = (bf16_t*)(ws + 10 * MB);   // [2048][1024]       4 MiB
  bf16_t* Wot  = (bf16_t*)(ws + 14 * MB);   // [1024][1024]       2 MiB
  bf16_t* Qw   = (bf16_t*)(ws + 16 * MB);   // [32][2048][64]     8 MiB
  bf16_t* Kw   = (bf16_t*)(ws + 24 * MB);   // [32][2048][64]     8 MiB
  bf16_t* Vtw  = (bf16_t*)(ws + 32 * MB);   // [32][64][2048]     8 MiB
  bf16_t* Aw   = (bf16_t*)(ws + 40 * MB);   // [4096][1024]       8 MiB

  cvt_kernel<<<4096, 256, 0, stream>>>(x, Xbf);
  dim3 tb(32, 8);
  transpose_kernel<<<dim3(32, 32), tb, 0, stream>>>(Wq, Wqt, 1024, 1024);
  transpose_kernel<<<dim3(64, 32), tb, 0, stream>>>(Wkv, Wkvt, 1024, 2048);
  transpose_kernel<<<dim3(32, 32), tb, 0, stream>>>(Wo, Wot, 1024, 1024);

  gemm_kernel<0><<<dim3(8, 32), 256, 0, stream>>>(Xbf, Wqt, Qw, nullptr, nullptr);
  gemm_kernel<1><<<dim3(16, 32), 256, 0, stream>>>(Xbf, Wkvt, Kw, Vtw, nullptr);
  attn_kernel<<<dim3(32, 32), 256, 0, stream>>>(Qw, Kw, Vtw, Aw);
  gemm_kernel<2><<<dim3(8, 32), 256, 0, stream>>>(Aw, Wot, nullptr, nullptr, out);
}

// Round 3
// 166.015 us; speedup vs baseline: 1.2758x; 1.2451x over previous
//
#include <hip/hip_runtime.h>
#include <cstdint>

// FlashAttention fused block: q/k/v proj -> causal attn -> out proj
// B=2, N=2048, DIM=1024, H=16, Dh=64. All compute bf16 MFMA + fp32 accum.
// R3: attn rewritten to 32x32 swapped-QK^T structure (m214-style):
//     lane owns one q-row; in-register softmax; in-register P exchange.

typedef __bf16 bf16_t;
typedef __bf16 bf16x8 __attribute__((ext_vector_type(8)));
typedef __bf16 bf16x4 __attribute__((ext_vector_type(4)));
typedef float  f32x4  __attribute__((ext_vector_type(4)));
typedef float  f32x16 __attribute__((ext_vector_type(16)));
typedef unsigned int u32;

#define QSCALE 0.18033688011112042f  /* 0.125 * log2(e) */

// global -> LDS direct DMA, 16B per lane. LDS dest must be uniform-base + lane*16.
__device__ __forceinline__ void gload_lds16(const void* gsrc, void* ldst) {
  __builtin_amdgcn_global_load_lds(
      (__attribute__((address_space(1))) void*)(uintptr_t)gsrc,
      (__attribute__((address_space(3))) void*)(uintptr_t)(uint32_t)(uintptr_t)ldst,
      16, 0, 0);
}

__device__ __forceinline__ u32 pkbf(float a, float b) {
  const u32 lo = (u32)__builtin_bit_cast(unsigned short, (bf16_t)a);
  const u32 hi = (u32)__builtin_bit_cast(unsigned short, (bf16_t)b);
  return (hi << 16) | lo;
}

// ---------------- prep: fp32 -> bf16 convert ----------------
__global__ __launch_bounds__(256) void cvt_kernel(const float* __restrict__ in,
                                                  bf16_t* __restrict__ out) {
  const int idx = (blockIdx.x * 256 + threadIdx.x) * 4;
  const float4 v = *(const float4*)(in + idx);
  bf16x4 o;
  o[0] = (bf16_t)v.x; o[1] = (bf16_t)v.y; o[2] = (bf16_t)v.z; o[3] = (bf16_t)v.w;
  *(bf16x4*)(out + idx) = o;
}

// ---------------- prep: W [K][Nn] fp32 -> Wt [Nn][K] bf16 ----------------
__global__ __launch_bounds__(256) void transpose_kernel(const float* __restrict__ W,
                                                        bf16_t* __restrict__ Wt,
                                                        int K, int Nn) {
  __shared__ float tile[32][33];
  const int bx = blockIdx.x, by = blockIdx.y;
  const int x = bx * 32 + threadIdx.x;
  #pragma unroll
  for (int r0 = 0; r0 < 32; r0 += 8) {
    const int r = r0 + threadIdx.y;
    tile[r][threadIdx.x] = W[(size_t)(by * 32 + r) * Nn + x];
  }
  __syncthreads();
  const int xo = by * 32 + threadIdx.x;
  #pragma unroll
  for (int r0 = 0; r0 < 32; r0 += 8) {
    const int r = r0 + threadIdx.y;
    Wt[(size_t)(bx * 32 + r) * K + xo] = (bf16_t)tile[threadIdx.x][r];
  }
}

// ---------------- GEMM: C[M][Nn] = A[M][1024] @ Bt[Nn][1024]^T ----------------
// 128x128 tile, BK=64, 4 waves (2x2 of 64x64), 16x16x32 bf16 MFMA.
// LDS chunk swizzle: physical chunk c holds logical chunk c ^ (row&7).
// 2-phase double-buffer: prefetch next K-tile, counted vmcnt(8).
// MODE 0: out0 = Q bf16 [bh][n][64], pre-scaled by 0.125*log2e
// MODE 1: ci<1024 -> out0 = K bf16 [bh][n][64]; ci>=1024 -> out1 = V^T bf16 [bh][64][n]
// MODE 2: outf = fp32 row-major [M][1024]
template <int MODE>
__global__ __launch_bounds__(256) void gemm_kernel(
    const bf16_t* __restrict__ A, const bf16_t* __restrict__ Bt,
    bf16_t* __restrict__ out0, bf16_t* __restrict__ out1,
    float* __restrict__ outf) {
  constexpr int KD = 1024;
  __shared__ bf16_t As[2][128][64];
  __shared__ bf16_t Bs[2][128][64];
  const int t = threadIdx.x;
  const int lane = t & 63, w = t >> 6;
  const int wr = w >> 1, wc = w & 1;
  const int lrow = lane & 15, lq = lane >> 4;
  const int bm = blockIdx.y * 128, bn = blockIdx.x * 128;

  f32x4 acc[4][4] = {};

  auto stage = [&](int buf, int k0) {
    #pragma unroll
    for (int i = 0; i < 4; ++i) {
      const int lin = i * 256 + t;
      const int row = lin >> 3;
      const int sc = (lin & 7) ^ (row & 7);
      gload_lds16(A + (size_t)(bm + row) * KD + k0 + sc * 8,
                  &As[buf][0][0] + lin * 8);
      gload_lds16(Bt + (size_t)(bn + row) * KD + k0 + sc * 8,
                  &Bs[buf][0][0] + lin * 8);
    }
  };

  stage(0, 0);
  for (int kt = 0; kt < KD / 64; ++kt) {
    const int cur = kt & 1;
    if (kt + 1 < KD / 64) {
      stage(cur ^ 1, (kt + 1) * 64);
      asm volatile("s_waitcnt vmcnt(8)" ::: "memory");
    } else {
      asm volatile("s_waitcnt vmcnt(0)" ::: "memory");
    }
    __builtin_amdgcn_s_barrier();

    #pragma unroll
    for (int kk = 0; kk < 2; ++kk) {
      bf16x8 aF[4], bF[4];
      #pragma unroll
      for (int m = 0; m < 4; ++m) {
        const int row = wr * 64 + m * 16 + lrow;
        const int ch = (kk * 4 + lq) ^ (row & 7);
        aF[m] = *(const bf16x8*)&As[cur][row][ch * 8];
      }
      #pragma unroll
      for (int n = 0; n < 4; ++n) {
        const int row = wc * 64 + n * 16 + lrow;
        const int ch = (kk * 4 + lq) ^ (row & 7);
        bF[n] = *(const bf16x8*)&Bs[cur][row][ch * 8];
      }
      #pragma unroll
      for (int m = 0; m < 4; ++m)
        #pragma unroll
        for (int n = 0; n < 4; ++n)
          acc[m][n] = __builtin_amdgcn_mfma_f32_16x16x32_bf16(aF[m], bF[n],
                                                              acc[m][n], 0, 0, 0);
    }
    asm volatile("s_waitcnt lgkmcnt(0)" ::: "memory");
    __builtin_amdgcn_s_barrier();
  }

  #pragma unroll
  for (int m = 0; m < 4; ++m) {
    const int ri = bm + wr * 64 + m * 16 + lq * 4;
    #pragma unroll
    for (int n = 0; n < 4; ++n) {
      const int ci = bn + wc * 64 + n * 16 + lrow;
      const f32x4 v = acc[m][n];
      if (MODE == 2) {
        #pragma unroll
        for (int r = 0; r < 4; ++r)
          outf[(size_t)(ri + r) * 1024 + ci] = v[r];
      } else {
        if (MODE == 0 || ci < 1024) {
          const int h = (ci & 1023) >> 6, d = ci & 63;
          const float sc = (MODE == 0) ? QSCALE : 1.0f;
          #pragma unroll
          for (int r = 0; r < 4; ++r) {
            const int i = ri + r;
            const int b = i >> 11, ii = i & 2047;
            out0[(((size_t)(b * 16 + h) * 2048 + ii) << 6) + d] = (bf16_t)(v[r] * sc);
          }
        } else {
          const int hd = ci - 1024;
          const int h = hd >> 6, d = hd & 63;
          const int b = ri >> 11, ii = ri & 2047;
          bf16x4 pk;
          pk[0] = (bf16_t)v[0]; pk[1] = (bf16_t)v[1];
          pk[2] = (bf16_t)v[2]; pk[3] = (bf16_t)v[3];
          *(bf16x4*)(out1 + (((size_t)(b * 16 + h) * 64 + d) << 11) + ii) = pk;
        }
      }
    }
  }
}

// ---------------- flash attention (32x32 swapped structure) ----------------
// grid: (16 qblocks, 32 bh). 4 waves x 32 q-rows = 128 q/block; KV tiles of 64.
// Swapped QK^T: S^T = mfma(K, Q) -> lane q=lane&31 holds P-row in registers.
// Swapped PV:   O^T = mfma(Vt, P) -> col=q matches softmax lane ownership.
// Q pre-scaled by 0.125*log2e -> exp2 directly. Double-buffered K/Vt, vmcnt(4).
__global__ __launch_bounds__(256) void attn_kernel(
    const bf16_t* __restrict__ Qw, const bf16_t* __restrict__ Kw,
    const bf16_t* __restrict__ Vtw, bf16_t* __restrict__ Ow) {
  __shared__ bf16_t Ks[2][64][64];
  __shared__ bf16_t Vs[2][64][64];   // logical [d][j], chunk-swizzled
  const int t = threadIdx.x;
  const int lane = t & 63, w = t >> 6;
  const int l31 = lane & 31, hi = lane >> 5;
  const int bh = blockIdx.y;
  const int qb = gridDim.x - 1 - blockIdx.x;  // longest blocks first
  const int qw0 = qb * 128 + w * 32;
  const int qg = qw0 + l31;                   // this lane's q row
  const bf16_t* Qb = Qw + (size_t)bh * 2048 * 64;
  const bf16_t* Kb = Kw + (size_t)bh * 2048 * 64;
  const bf16_t* Vb = Vtw + (size_t)bh * 64 * 2048;

  // Q frags (B-operand): row=q=l31, k = ks*16 + hi*8 + e
  bf16x8 qf0 = *(const bf16x8*)(Qb + (size_t)qg * 64 +  0 + hi * 8);
  bf16x8 qf1 = *(const bf16x8*)(Qb + (size_t)qg * 64 + 16 + hi * 8);
  bf16x8 qf2 = *(const bf16x8*)(Qb + (size_t)qg * 64 + 32 + hi * 8);
  bf16x8 qf3 = *(const bf16x8*)(Qb + (size_t)qg * 64 + 48 + hi * 8);

  f32x16 acc0 = {}, acc1 = {};  // O^T: col=q=l31, row d_local=(r&3)+8*(r>>2)+4hi, d=dt*32+dl
  float m_run = -1e30f, l_run = 0.f;

  auto stage = [&](int buf, int jb) {
    #pragma unroll
    for (int i = 0; i < 2; ++i) {  // 64 rows x 8 chunks = 512 / 256 thr
      const int lin = i * 256 + t;
      const int row = lin >> 3;
      const int sc = (lin & 7) ^ (row & 7);
      gload_lds16(Kb + (size_t)(jb + row) * 64 + sc * 8, &Ks[buf][0][0] + lin * 8);
      gload_lds16(Vb + (size_t)row * 2048 + jb + sc * 8, &Vs[buf][0][0] + lin * 8);
    }
  };

  const int ntiles = 2 * qb + 2;
  const int qwmax = qw0 + 31;
  stage(0, 0);
  for (int jt = 0; jt < ntiles; ++jt) {
    const int jb = jt * 64;
    const int cur = jt & 1;
    if (jt + 1 < ntiles) {
      stage(cur ^ 1, jb + 64);
      asm volatile("s_waitcnt vmcnt(4)" ::: "memory");
    } else {
      asm volatile("s_waitcnt vmcnt(0)" ::: "memory");
    }
    __builtin_amdgcn_s_barrier();

    if (jb <= qwmax) {  // wave-uniform: skip fully-masked trailing tiles
      // ---- S^T = mfma(K, Q): D[j][q], col=q=l31, j_loc=(r&3)+8*(r>>2)+4hi ----
      f32x16 st0 = {}, st1 = {};
      #pragma unroll
      for (int ks = 0; ks < 4; ++ks) {
        const int r0 = l31, r1 = 32 + l31;
        const bf16x8 kf0 = *(const bf16x8*)&Ks[cur][r0][(((ks * 2 + hi) ^ (r0 & 7)) * 8)];
        const bf16x8 kf1 = *(const bf16x8*)&Ks[cur][r1][(((ks * 2 + hi) ^ (r1 & 7)) * 8)];
        const bf16x8 qk = ks == 0 ? qf0 : ks == 1 ? qf1 : ks == 2 ? qf2 : qf3;
        st0 = __builtin_amdgcn_mfma_f32_32x32x16_bf16(kf0, qk, st0, 0, 0, 0);
        st1 = __builtin_amdgcn_mfma_f32_32x32x16_bf16(kf1, qk, st1, 0, 0, 0);
      }

      // ---- causal mask (only near-diagonal tiles) ----
      if (jb + 63 > qw0) {
        const int thr = qg - jb;  // mask where j_loc > thr
        #pragma unroll
        for (int r = 0; r < 16; ++r) {
          const int jl = (r & 3) + 8 * (r >> 2) + 4 * hi;
          st0[r] = (jl > thr) ? -1e30f : st0[r];
          st1[r] = (32 + jl > thr) ? -1e30f : st1[r];
        }
      }

      // ---- row max: in-register tree + one cross-half shfl ----
      float t8[8];
      #pragma unroll
      for (int i = 0; i < 8; ++i)
        t8[i] = fmaxf(fmaxf(st0[i], st0[i + 8]), fmaxf(st1[i], st1[i + 8]));
      #pragma unroll
      for (int i = 0; i < 4; ++i) t8[i] = fmaxf(t8[i], t8[i + 4]);
      float mx = fmaxf(fmaxf(t8[0], t8[1]), fmaxf(t8[2], t8[3]));
      mx = fmaxf(mx, __shfl_xor(mx, 32, 64));
      const float m_new = fmaxf(m_run, mx);
      const float corr = exp2f(m_run - m_new);
      m_run = m_new;

      // ---- exp + row sum ----
      #pragma unroll
      for (int r = 0; r < 16; ++r) {
        st0[r] = exp2f(st0[r] - m_new);
        st1[r] = exp2f(st1[r] - m_new);
      }
      float s8[8];
      #pragma unroll
      for (int i = 0; i < 8; ++i)
        s8[i] = (st0[i] + st0[i + 8]) + (st1[i] + st1[i + 8]);
      #pragma unroll
      for (int i = 0; i < 4; ++i) s8[i] += s8[i + 4];
      float sum = (s8[0] + s8[1]) + (s8[2] + s8[3]);
      sum += __shfl_xor(sum, 32, 64);
      l_run = l_run * corr + sum;

      // ---- rescale O ----
      #pragma unroll
      for (int r = 0; r < 16; ++r) { acc0[r] *= corr; acc1[r] *= corr; }

      // ---- P -> bf16 B-operand frags via packed cross-half exchange ----
      u32 Wa[8], Wb[8], Xa[8], Xb[8];
      #pragma unroll
      for (int g = 0; g < 8; ++g) {
        Wa[g] = pkbf(st0[2 * g], st0[2 * g + 1]);
        Wb[g] = pkbf(st1[2 * g], st1[2 * g + 1]);
      }
      #pragma unroll
      for (int g = 0; g < 8; ++g) {
        Xa[g] = (u32)__shfl_xor((int)Wa[g], 32, 64);
        Xb[g] = (u32)__shfl_xor((int)Wb[g], 32, 64);
      }
      uint4 u0, u1, u2, u3;
      if (hi) {
        u0 = make_uint4(Xa[2], Xa[3], Wa[2], Wa[3]);
        u1 = make_uint4(Xa[6], Xa[7], Wa[6], Wa[7]);
        u2 = make_uint4(Xb[2], Xb[3], Wb[2], Wb[3]);
        u3 = make_uint4(Xb[6], Xb[7], Wb[6], Wb[7]);
      } else {
        u0 = make_uint4(Wa[0], Wa[1], Xa[0], Xa[1]);
        u1 = make_uint4(Wa[4], Wa[5], Xa[4], Xa[5]);
        u2 = make_uint4(Wb[0], Wb[1], Xb[0], Xb[1]);
        u3 = make_uint4(Wb[4], Wb[5], Xb[4], Xb[5]);
      }
      const bf16x8 pf0 = __builtin_bit_cast(bf16x8, u0);
      const bf16x8 pf1 = __builtin_bit_cast(bf16x8, u1);
      const bf16x8 pf2 = __builtin_bit_cast(bf16x8, u2);
      const bf16x8 pf3 = __builtin_bit_cast(bf16x8, u3);

      // ---- O^T += mfma(Vt, P): A rows=d, B rows=q, k=j ----
      #pragma unroll
      for (int tt = 0; tt < 4; ++tt) {
        const bf16x8 pf = tt == 0 ? pf0 : tt == 1 ? pf1 : tt == 2 ? pf2 : pf3;
        const int r0 = l31, r1 = 32 + l31;
        const bf16x8 vf0 = *(const bf16x8*)&Vs[cur][r0][(((tt * 2 + hi) ^ (r0 & 7)) * 8)];
        const bf16x8 vf1 = *(const bf16x8*)&Vs[cur][r1][(((tt * 2 + hi) ^ (r1 & 7)) * 8)];
        acc0 = __builtin_amdgcn_mfma_f32_32x32x16_bf16(vf0, pf, acc0, 0, 0, 0);
        acc1 = __builtin_amdgcn_mfma_f32_32x32x16_bf16(vf1, pf, acc1, 0, 0, 0);
      }
    }
    asm volatile("s_waitcnt lgkmcnt(0)" ::: "memory");
    __builtin_amdgcn_s_barrier();
  }

  // ---- epilogue: lane q writes its row; d = dt*32 + 8*(r>>2) + 4*hi + (r&3) ----
  const float inv = 1.0f / l_run;
  const int b = bh >> 4, h = bh & 15;
  bf16_t* Obase = Ow + (((size_t)(b * 2048 + qg)) << 10) + h * 64;
  #pragma unroll
  for (int g = 0; g < 4; ++g) {
    bf16x4 p0, p1;
    #pragma unroll
    for (int j = 0; j < 4; ++j) {
      p0[j] = (bf16_t)(acc0[4 * g + j] * inv);
      p1[j] = (bf16_t)(acc1[4 * g + j] * inv);
    }
    *(bf16x4*)(Obase + 8 * g + 4 * hi) = p0;
    *(bf16x4*)(Obase + 32 + 8 * g + 4 * hi) = p1;
  }
}

// ---------------- orchestration ----------------
extern "C" void kernel_launch(void* const* d_in, const int* in_sizes, int n_in,
                              void* d_out, int out_size, void* d_ws, size_t ws_size,
                              hipStream_t stream) {
  const float* x   = (const float*)d_in[0];
  const float* Wq  = (const float*)d_in[1];
  const float* Wkv = (const float*)d_in[2];
  const float* Wo  = (const float*)d_in[3];
  float* out = (float*)d_out;
  char* ws = (char*)d_ws;

  const size_t MB = 1024 * 1024;
  bf16_t* Xbf  = (bf16_t*)(ws);             // [4096][1024]       8 MiB
  bf16_t* Wqt  = (bf16_t*)(ws + 8 * MB);    // [1024][1024]       2 MiB
  bf16_t* Wkvt = (bf16_t*)(ws + 10 * MB);   // [2048][1024]       4 MiB
  bf16_t* Wot  = (bf16_t*)(ws + 14 * MB);   // [1024][1024]       2 MiB
  bf16_t* Qw   = (bf16_t*)(ws + 16 * MB);   // [32][2048][64]     8 MiB (pre-scaled)
  bf16_t* Kw   = (bf16_t*)(ws + 24 * MB);   // [32][2048][64]     8 MiB
  bf16_t* Vtw  = (bf16_t*)(ws + 32 * MB);   // [32][64][2048]     8 MiB
  bf16_t* Aw   = (bf16_t*)(ws + 40 * MB);   // [4096][1024]       8 MiB

  cvt_kernel<<<4096, 256, 0, stream>>>(x, Xbf);
  dim3 tb(32, 8);
  transpose_kernel<<<dim3(32, 32), tb, 0, stream>>>(Wq, Wqt, 1024, 1024);
  transpose_kernel<<<dim3(64, 32), tb, 0, stream>>>(Wkv, Wkvt, 1024, 2048);
  transpose_kernel<<<dim3(32, 32), tb, 0, stream>>>(Wo, Wot, 1024, 1024);

  gemm_kernel<0><<<dim3(8, 32), 256, 0, stream>>>(Xbf, Wqt, Qw, nullptr, nullptr);
  gemm_kernel<1><<<dim3(16, 32), 256, 0, stream>>>(Xbf, Wkvt, Kw, Vtw, nullptr);
  attn_kernel<<<dim3(16, 32), 256, 0, stream>>>(Qw, Kw, Vtw, Aw);
  gemm_kernel<2><<<dim3(8, 32), 256, 0, stream>>>(Aw, Wot, nullptr, nullptr, out);
}

// Round 4
// 150.848 us; speedup vs baseline: 1.4041x; 1.1005x over previous
//
#include <hip/hip_runtime.h>
#include <cstdint>

// FlashAttention fused block: q/k/v proj -> causal attn -> out proj
// B=2, N=2048, DIM=1024, H=16, Dh=64. All compute bf16 MFMA + fp32 accum.
// R4: attn is barrier-free & LDS-free. Q/K/V are written by the projection
// GEMMs in MFMA-fragment-major layout, so attn operand loads are perfectly
// coalesced 1KB global loads (L2-resident). One wave per block.

typedef __bf16 bf16_t;
typedef __bf16 bf16x8 __attribute__((ext_vector_type(8)));
typedef __bf16 bf16x4 __attribute__((ext_vector_type(4)));
typedef float  f32x4  __attribute__((ext_vector_type(4)));
typedef float  f32x16 __attribute__((ext_vector_type(16)));
typedef unsigned int u32;

#define QSCALE 0.18033688011112042f  /* 0.125 * log2(e) */

// Fragment-major layouts (per bh, 131072 elems = 2048x64):
//  K/Q: elem = bh*131072 + ((q>>6)*8 + (d>>4)*2 + ((q>>5)&1))*512
//             + (((d>>3)&1)*32 + (q&31))*8 + (d&7)
//  V^T: elem = bh*131072 + ((j>>6)*8 + ((j&63)>>4)*2 + (d>>5))*512
//             + (((j>>3)&1)*32 + (d&31))*8 + (j&7)

// global -> LDS direct DMA, 16B per lane. LDS dest must be uniform-base + lane*16.
__device__ __forceinline__ void gload_lds16(const void* gsrc, void* ldst) {
  __builtin_amdgcn_global_load_lds(
      (__attribute__((address_space(1))) void*)(uintptr_t)gsrc,
      (__attribute__((address_space(3))) void*)(uintptr_t)(uint32_t)(uintptr_t)ldst,
      16, 0, 0);
}

__device__ __forceinline__ u32 pkbf(float a, float b) {
  const u32 lo = (u32)__builtin_bit_cast(unsigned short, (bf16_t)a);
  const u32 hi = (u32)__builtin_bit_cast(unsigned short, (bf16_t)b);
  return (hi << 16) | lo;
}

// ---------------- prep: fp32 -> bf16 convert ----------------
__global__ __launch_bounds__(256) void cvt_kernel(const float* __restrict__ in,
                                                  bf16_t* __restrict__ out) {
  const int idx = (blockIdx.x * 256 + threadIdx.x) * 4;
  const float4 v = *(const float4*)(in + idx);
  bf16x4 o;
  o[0] = (bf16_t)v.x; o[1] = (bf16_t)v.y; o[2] = (bf16_t)v.z; o[3] = (bf16_t)v.w;
  *(bf16x4*)(out + idx) = o;
}

// ---------------- prep: W [K][Nn] fp32 -> Wt [Nn][K] bf16 ----------------
__global__ __launch_bounds__(256) void transpose_kernel(const float* __restrict__ W,
                                                        bf16_t* __restrict__ Wt,
                                                        int K, int Nn) {
  __shared__ float tile[32][33];
  const int bx = blockIdx.x, by = blockIdx.y;
  const int x = bx * 32 + threadIdx.x;
  #pragma unroll
  for (int r0 = 0; r0 < 32; r0 += 8) {
    const int r = r0 + threadIdx.y;
    tile[r][threadIdx.x] = W[(size_t)(by * 32 + r) * Nn + x];
  }
  __syncthreads();
  const int xo = by * 32 + threadIdx.x;
  #pragma unroll
  for (int r0 = 0; r0 < 32; r0 += 8) {
    const int r = r0 + threadIdx.y;
    Wt[(size_t)(bx * 32 + r) * K + xo] = (bf16_t)tile[threadIdx.x][r];
  }
}

// ---------------- GEMM: C[M][Nn] = A[M][1024] @ Bt[Nn][1024]^T ----------------
// 128x128 tile, BK=64, 4 waves (2x2 of 64x64), 16x16x32 bf16 MFMA.
// LDS chunk swizzle: physical chunk c holds logical chunk c ^ (row&7).
// 2-phase double-buffer: prefetch next K-tile, counted vmcnt(8).
// MODE 0: out0 = Q fragment-major, pre-scaled by 0.125*log2e
// MODE 1: ci<1024 -> out0 = K fragment-major; ci>=1024 -> out1 = V^T fragment-major
// MODE 2: outf = fp32 row-major [M][1024]
template <int MODE>
__global__ __launch_bounds__(256) void gemm_kernel(
    const bf16_t* __restrict__ A, const bf16_t* __restrict__ Bt,
    bf16_t* __restrict__ out0, bf16_t* __restrict__ out1,
    float* __restrict__ outf) {
  constexpr int KD = 1024;
  __shared__ bf16_t As[2][128][64];
  __shared__ bf16_t Bs[2][128][64];
  const int t = threadIdx.x;
  const int lane = t & 63, w = t >> 6;
  const int wr = w >> 1, wc = w & 1;
  const int lrow = lane & 15, lq = lane >> 4;
  const int bm = blockIdx.y * 128, bn = blockIdx.x * 128;

  f32x4 acc[4][4] = {};

  auto stage = [&](int buf, int k0) {
    #pragma unroll
    for (int i = 0; i < 4; ++i) {
      const int lin = i * 256 + t;
      const int row = lin >> 3;
      const int sc = (lin & 7) ^ (row & 7);
      gload_lds16(A + (size_t)(bm + row) * KD + k0 + sc * 8,
                  &As[buf][0][0] + lin * 8);
      gload_lds16(Bt + (size_t)(bn + row) * KD + k0 + sc * 8,
                  &Bs[buf][0][0] + lin * 8);
    }
  };

  stage(0, 0);
  for (int kt = 0; kt < KD / 64; ++kt) {
    const int cur = kt & 1;
    if (kt + 1 < KD / 64) {
      stage(cur ^ 1, (kt + 1) * 64);
      asm volatile("s_waitcnt vmcnt(8)" ::: "memory");
    } else {
      asm volatile("s_waitcnt vmcnt(0)" ::: "memory");
    }
    __builtin_amdgcn_s_barrier();

    #pragma unroll
    for (int kk = 0; kk < 2; ++kk) {
      bf16x8 aF[4], bF[4];
      #pragma unroll
      for (int m = 0; m < 4; ++m) {
        const int row = wr * 64 + m * 16 + lrow;
        const int ch = (kk * 4 + lq) ^ (row & 7);
        aF[m] = *(const bf16x8*)&As[cur][row][ch * 8];
      }
      #pragma unroll
      for (int n = 0; n < 4; ++n) {
        const int row = wc * 64 + n * 16 + lrow;
        const int ch = (kk * 4 + lq) ^ (row & 7);
        bF[n] = *(const bf16x8*)&Bs[cur][row][ch * 8];
      }
      #pragma unroll
      for (int m = 0; m < 4; ++m)
        #pragma unroll
        for (int n = 0; n < 4; ++n)
          acc[m][n] = __builtin_amdgcn_mfma_f32_16x16x32_bf16(aF[m], bF[n],
                                                              acc[m][n], 0, 0, 0);
    }
    asm volatile("s_waitcnt lgkmcnt(0)" ::: "memory");
    __builtin_amdgcn_s_barrier();
  }

  #pragma unroll
  for (int m = 0; m < 4; ++m) {
    const int ri = bm + wr * 64 + m * 16 + lq * 4;
    #pragma unroll
    for (int n = 0; n < 4; ++n) {
      const int ci = bn + wc * 64 + n * 16 + lrow;
      const f32x4 v = acc[m][n];
      if (MODE == 2) {
        #pragma unroll
        for (int r = 0; r < 4; ++r)
          outf[(size_t)(ri + r) * 1024 + ci] = v[r];
      } else {
        if (MODE == 0 || ci < 1024) {
          const int h = (ci & 1023) >> 6, d = ci & 63;
          const float sc = (MODE == 0) ? QSCALE : 1.0f;
          const int fpart = (d >> 4) * 2;
          const int lpart = ((d >> 3) & 1) * 32;
          const int epart = d & 7;
          #pragma unroll
          for (int r = 0; r < 4; ++r) {
            const int i = ri + r;
            const int b = i >> 11, q = i & 2047;
            const size_t elem = (size_t)(b * 16 + h) * 131072
                + (size_t)((q >> 6) * 8 + fpart + ((q >> 5) & 1)) * 512
                + (lpart + (q & 31)) * 8 + epart;
            out0[elem] = (bf16_t)(v[r] * sc);
          }
        } else {
          const int hd = ci - 1024;
          const int h = hd >> 6, d = hd & 63;
          const int b = ri >> 11, j0 = ri & 2047;
          bf16x4 pk;
          pk[0] = (bf16_t)v[0]; pk[1] = (bf16_t)v[1];
          pk[2] = (bf16_t)v[2]; pk[3] = (bf16_t)v[3];
          const size_t elem = (size_t)(b * 16 + h) * 131072
              + (size_t)((j0 >> 6) * 8 + ((j0 & 63) >> 4) * 2 + (d >> 5)) * 512
              + ((((j0 >> 3) & 1) * 32) + (d & 31)) * 8 + (j0 & 7);
          *(bf16x4*)(out1 + elem) = pk;
        }
      }
    }
  }
}

// ---------------- flash attention (barrier-free, LDS-free) ----------------
// grid: (64 q-strips, 32 bh), block = 1 wave (64 thr). Each wave owns 32 q-rows.
// Swapped QK^T: S^T = mfma(Kfrag, Qfrag) -> lane q=lane&31 holds P-row in regs.
// Swapped PV:   O^T = mfma(Vfrag, Pfrag). All operands direct from L2,
// fragment-major coalesced. Q pre-scaled by 0.125*log2e -> exp2 directly.
__global__ __launch_bounds__(64) void attn_kernel(
    const bf16_t* __restrict__ Qf, const bf16_t* __restrict__ Kf,
    const bf16_t* __restrict__ Vf, bf16_t* __restrict__ Ow) {
  const int lane = threadIdx.x;
  const int l31 = lane & 31, hi = lane >> 5;
  const int bh = blockIdx.y;
  const int qs = gridDim.x - 1 - blockIdx.x;  // longest strips dispatched first
  const int qw0 = qs * 32;
  const int qg = qw0 + l31;                   // this lane's q row
  const bf16_t* Qb = Qf + (size_t)bh * 131072 + (size_t)(qs >> 1) * 4096 + (qs & 1) * 512;
  const bf16_t* Kb = Kf + (size_t)bh * 131072;
  const bf16_t* Vb = Vf + (size_t)bh * 131072;

  // Q frags (B-operand): row=q=l31, k = ks*16 + hi*8 + e
  bf16x8 qf[4];
  #pragma unroll
  for (int ks = 0; ks < 4; ++ks)
    qf[ks] = *(const bf16x8*)(Qb + ks * 1024 + lane * 8);

  f32x16 acc0 = {}, acc1 = {};  // O^T: col=q=l31, d = 32*t + 8*(r>>2) + 4*hi + (r&3)
  float m_run = -1e30f, l_run = 0.f;
  const int nt = (qs >> 1) + 1;

  for (int jt = 0; jt < nt; ++jt) {
    const bf16_t* Kt = Kb + (size_t)jt * 4096;
    const bf16_t* Vt = Vb + (size_t)jt * 4096;

    // ---- K frags, coalesced 1KB loads ----
    bf16x8 kf0[4], kf1[4];
    #pragma unroll
    for (int ks = 0; ks < 4; ++ks) {
      kf0[ks] = *(const bf16x8*)(Kt + (ks * 2 + 0) * 512 + lane * 8);
      kf1[ks] = *(const bf16x8*)(Kt + (ks * 2 + 1) * 512 + lane * 8);
    }

    // ---- S^T = mfma(K, Q): col=q=l31, j_loc=(r&3)+8*(r>>2)+4hi ----
    f32x16 st0 = {}, st1 = {};
    #pragma unroll
    for (int ks = 0; ks < 4; ++ks) {
      st0 = __builtin_amdgcn_mfma_f32_32x32x16_bf16(kf0[ks], qf[ks], st0, 0, 0, 0);
      st1 = __builtin_amdgcn_mfma_f32_32x32x16_bf16(kf1[ks], qf[ks], st1, 0, 0, 0);
    }

    // ---- V frags issued now; latency hides under softmax ----
    bf16x8 vf0[4], vf1[4];
    #pragma unroll
    for (int tt = 0; tt < 4; ++tt) {
      vf0[tt] = *(const bf16x8*)(Vt + (tt * 2 + 0) * 512 + lane * 8);
      vf1[tt] = *(const bf16x8*)(Vt + (tt * 2 + 1) * 512 + lane * 8);
    }

    // ---- causal mask (only the last tile per wave touches the diagonal) ----
    if (jt == nt - 1) {
      const int thr = qg - jt * 64;  // mask where j_loc > thr
      #pragma unroll
      for (int r = 0; r < 16; ++r) {
        const int jl = (r & 3) + 8 * (r >> 2) + 4 * hi;
        st0[r] = (jl > thr) ? -1e30f : st0[r];
        st1[r] = (32 + jl > thr) ? -1e30f : st1[r];
      }
    }

    // ---- row max: in-register tree + one cross-half shfl ----
    float t8[8];
    #pragma unroll
    for (int i = 0; i < 8; ++i)
      t8[i] = fmaxf(fmaxf(st0[i], st0[i + 8]), fmaxf(st1[i], st1[i + 8]));
    #pragma unroll
    for (int i = 0; i < 4; ++i) t8[i] = fmaxf(t8[i], t8[i + 4]);
    float mx = fmaxf(fmaxf(t8[0], t8[1]), fmaxf(t8[2], t8[3]));
    mx = fmaxf(mx, __shfl_xor(mx, 32, 64));
    const float m_new = fmaxf(m_run, mx);
    const float corr = exp2f(m_run - m_new);
    m_run = m_new;

    // ---- exp + row sum ----
    #pragma unroll
    for (int r = 0; r < 16; ++r) {
      st0[r] = exp2f(st0[r] - m_new);
      st1[r] = exp2f(st1[r] - m_new);
    }
    float s8[8];
    #pragma unroll
    for (int i = 0; i < 8; ++i)
      s8[i] = (st0[i] + st0[i + 8]) + (st1[i] + st1[i + 8]);
    #pragma unroll
    for (int i = 0; i < 4; ++i) s8[i] += s8[i + 4];
    float sum = (s8[0] + s8[1]) + (s8[2] + s8[3]);
    sum += __shfl_xor(sum, 32, 64);
    l_run = l_run * corr + sum;

    // ---- rescale O ----
    #pragma unroll
    for (int r = 0; r < 16; ++r) { acc0[r] *= corr; acc1[r] *= corr; }

    // ---- P -> bf16 B-operand frags via packed cross-half exchange ----
    u32 Wa[8], Wb[8], Xa[8], Xb[8];
    #pragma unroll
    for (int g = 0; g < 8; ++g) {
      Wa[g] = pkbf(st0[2 * g], st0[2 * g + 1]);
      Wb[g] = pkbf(st1[2 * g], st1[2 * g + 1]);
    }
    #pragma unroll
    for (int g = 0; g < 8; ++g) {
      Xa[g] = (u32)__shfl_xor((int)Wa[g], 32, 64);
      Xb[g] = (u32)__shfl_xor((int)Wb[g], 32, 64);
    }
    uint4 u0, u1, u2, u3;
    if (hi) {
      u0 = make_uint4(Xa[2], Xa[3], Wa[2], Wa[3]);
      u1 = make_uint4(Xa[6], Xa[7], Wa[6], Wa[7]);
      u2 = make_uint4(Xb[2], Xb[3], Wb[2], Wb[3]);
      u3 = make_uint4(Xb[6], Xb[7], Wb[6], Wb[7]);
    } else {
      u0 = make_uint4(Wa[0], Wa[1], Xa[0], Xa[1]);
      u1 = make_uint4(Wa[4], Wa[5], Xa[4], Xa[5]);
      u2 = make_uint4(Wb[0], Wb[1], Xb[0], Xb[1]);
      u3 = make_uint4(Wb[4], Wb[5], Xb[4], Xb[5]);
    }
    const bf16x8 pf0 = __builtin_bit_cast(bf16x8, u0);
    const bf16x8 pf1 = __builtin_bit_cast(bf16x8, u1);
    const bf16x8 pf2 = __builtin_bit_cast(bf16x8, u2);
    const bf16x8 pf3 = __builtin_bit_cast(bf16x8, u3);

    // ---- O^T += mfma(V, P) ----
    #pragma unroll
    for (int tt = 0; tt < 4; ++tt) {
      const bf16x8 pf = tt == 0 ? pf0 : tt == 1 ? pf1 : tt == 2 ? pf2 : pf3;
      acc0 = __builtin_amdgcn_mfma_f32_32x32x16_bf16(vf0[tt], pf, acc0, 0, 0, 0);
      acc1 = __builtin_amdgcn_mfma_f32_32x32x16_bf16(vf1[tt], pf, acc1, 0, 0, 0);
    }
  }

  // ---- epilogue: lane q writes its row; d = 32*t + 8*g + 4*hi + 0..3 ----
  const float inv = 1.0f / l_run;
  const int b = bh >> 4, h = bh & 15;
  bf16_t* Obase = Ow + (((size_t)(b * 2048 + qg)) << 10) + h * 64;
  #pragma unroll
  for (int g = 0; g < 4; ++g) {
    bf16x4 p0, p1;
    #pragma unroll
    for (int j = 0; j < 4; ++j) {
      p0[j] = (bf16_t)(acc0[4 * g + j] * inv);
      p1[j] = (bf16_t)(acc1[4 * g + j] * inv);
    }
    *(bf16x4*)(Obase + 8 * g + 4 * hi) = p0;
    *(bf16x4*)(Obase + 32 + 8 * g + 4 * hi) = p1;
  }
}

// ---------------- orchestration ----------------
extern "C" void kernel_launch(void* const* d_in, const int* in_sizes, int n_in,
                              void* d_out, int out_size, void* d_ws, size_t ws_size,
                              hipStream_t stream) {
  const float* x   = (const float*)d_in[0];
  const float* Wq  = (const float*)d_in[1];
  const float* Wkv = (const float*)d_in[2];
  const float* Wo  = (const float*)d_in[3];
  float* out = (float*)d_out;
  char* ws = (char*)d_ws;

  const size_t MB = 1024 * 1024;
  bf16_t* Xbf  = (bf16_t*)(ws);             // [4096][1024]       8 MiB
  bf16_t* Wqt  = (bf16_t*)(ws + 8 * MB);    // [1024][1024]       2 MiB
  bf16_t* Wkvt = (bf16_t*)(ws + 10 * MB);   // [2048][1024]       4 MiB
  bf16_t* Wot  = (bf16_t*)(ws + 14 * MB);   // [1024][1024]       2 MiB
  bf16_t* Qw   = (bf16_t*)(ws + 16 * MB);   // frag-major Q       8 MiB (pre-scaled)
  bf16_t* Kw   = (bf16_t*)(ws + 24 * MB);   // frag-major K       8 MiB
  bf16_t* Vtw  = (bf16_t*)(ws + 32 * MB);   // frag-major V^T     8 MiB
  bf16_t* Aw   = (bf16_t*)(ws + 40 * MB);   // [4096][1024]       8 MiB

  cvt_kernel<<<4096, 256, 0, stream>>>(x, Xbf);
  dim3 tb(32, 8);
  transpose_kernel<<<dim3(32, 32), tb, 0, stream>>>(Wq, Wqt, 1024, 1024);
  transpose_kernel<<<dim3(64, 32), tb, 0, stream>>>(Wkv, Wkvt, 1024, 2048);
  transpose_kernel<<<dim3(32, 32), tb, 0, stream>>>(Wo, Wot, 1024, 1024);

  gemm_kernel<0><<<dim3(8, 32), 256, 0, stream>>>(Xbf, Wqt, Qw, nullptr, nullptr);
  gemm_kernel<1><<<dim3(16, 32), 256, 0, stream>>>(Xbf, Wkvt, Kw, Vtw, nullptr);
  attn_kernel<<<dim3(64, 32), 64, 0, stream>>>(Qw, Kw, Vtw, Aw);
  gemm_kernel<2><<<dim3(8, 32), 256, 0, stream>>>(Aw, Wot, nullptr, nullptr, out);
}

// Round 5
// 130.151 us; speedup vs baseline: 1.6274x; 1.1590x over previous
//
#include <hip/hip_runtime.h>
#include <cstdint>

// FlashAttention fused block: q/k/v proj -> causal attn -> out proj
// B=2, N=2048, DIM=1024, H=16, Dh=64. All compute bf16 MFMA + fp32 accum.
// R5: attn gets XCD-chunked bh mapping (L2 locality) + in-block 2-way KV
// split (2 waves/block -> 4096 waves, all co-resident). Q/KV projections
// fused into one GEMM (Nn=3072).

typedef __bf16 bf16_t;
typedef __bf16 bf16x8 __attribute__((ext_vector_type(8)));
typedef __bf16 bf16x4 __attribute__((ext_vector_type(4)));
typedef float  f32x4  __attribute__((ext_vector_type(4)));
typedef float  f32x16 __attribute__((ext_vector_type(16)));
typedef unsigned int u32;

#define QSCALE 0.18033688011112042f  /* 0.125 * log2(e) */

// Fragment-major layouts (per bh, 131072 elems = 2048x64):
//  K/Q: elem = bh*131072 + ((q>>6)*8 + (d>>4)*2 + ((q>>5)&1))*512
//             + (((d>>3)&1)*32 + (q&31))*8 + (d&7)
//  V^T: elem = bh*131072 + ((j>>6)*8 + ((j&63)>>4)*2 + (d>>5))*512
//             + (((j>>3)&1)*32 + (d&31))*8 + (j&7)

// global -> LDS direct DMA, 16B per lane. LDS dest must be uniform-base + lane*16.
__device__ __forceinline__ void gload_lds16(const void* gsrc, void* ldst) {
  __builtin_amdgcn_global_load_lds(
      (__attribute__((address_space(1))) void*)(uintptr_t)gsrc,
      (__attribute__((address_space(3))) void*)(uintptr_t)(uint32_t)(uintptr_t)ldst,
      16, 0, 0);
}

__device__ __forceinline__ u32 pkbf(float a, float b) {
  const u32 lo = (u32)__builtin_bit_cast(unsigned short, (bf16_t)a);
  const u32 hi = (u32)__builtin_bit_cast(unsigned short, (bf16_t)b);
  return (hi << 16) | lo;
}

// ---------------- prep: fp32 -> bf16 convert ----------------
__global__ __launch_bounds__(256) void cvt_kernel(const float* __restrict__ in,
                                                  bf16_t* __restrict__ out) {
  const int idx = (blockIdx.x * 256 + threadIdx.x) * 4;
  const float4 v = *(const float4*)(in + idx);
  bf16x4 o;
  o[0] = (bf16_t)v.x; o[1] = (bf16_t)v.y; o[2] = (bf16_t)v.z; o[3] = (bf16_t)v.w;
  *(bf16x4*)(out + idx) = o;
}

// ---------------- prep: W [K][Nn] fp32 -> Wt [Nn][K] bf16 ----------------
__global__ __launch_bounds__(256) void transpose_kernel(const float* __restrict__ W,
                                                        bf16_t* __restrict__ Wt,
                                                        int K, int Nn) {
  __shared__ float tile[32][33];
  const int bx = blockIdx.x, by = blockIdx.y;
  const int x = bx * 32 + threadIdx.x;
  #pragma unroll
  for (int r0 = 0; r0 < 32; r0 += 8) {
    const int r = r0 + threadIdx.y;
    tile[r][threadIdx.x] = W[(size_t)(by * 32 + r) * Nn + x];
  }
  __syncthreads();
  const int xo = by * 32 + threadIdx.x;
  #pragma unroll
  for (int r0 = 0; r0 < 32; r0 += 8) {
    const int r = r0 + threadIdx.y;
    Wt[(size_t)(bx * 32 + r) * K + xo] = (bf16_t)tile[threadIdx.x][r];
  }
}

// ---------------- GEMM: C[M][Nn] = A[M][1024] @ Bt[Nn][1024]^T ----------------
// 128x128 tile, BK=64, 4 waves (2x2 of 64x64), 16x16x32 bf16 MFMA.
// LDS chunk swizzle: physical chunk c holds logical chunk c ^ (row&7).
// 2-phase double-buffer: prefetch next K-tile, counted vmcnt(8).
// MODE 1: fused QKV. ci<1024 -> Q frag-major (scaled); <2048 -> K frag-major;
//         >=2048 -> V^T frag-major.
// MODE 2: outf = fp32 row-major [M][1024]
template <int MODE>
__global__ __launch_bounds__(256) void gemm_kernel(
    const bf16_t* __restrict__ A, const bf16_t* __restrict__ Bt,
    bf16_t* __restrict__ outQ, bf16_t* __restrict__ outK,
    bf16_t* __restrict__ outV, float* __restrict__ outf) {
  constexpr int KD = 1024;
  __shared__ bf16_t As[2][128][64];
  __shared__ bf16_t Bs[2][128][64];
  const int t = threadIdx.x;
  const int lane = t & 63, w = t >> 6;
  const int wr = w >> 1, wc = w & 1;
  const int lrow = lane & 15, lq = lane >> 4;
  const int bm = blockIdx.y * 128, bn = blockIdx.x * 128;

  f32x4 acc[4][4] = {};

  auto stage = [&](int buf, int k0) {
    #pragma unroll
    for (int i = 0; i < 4; ++i) {
      const int lin = i * 256 + t;
      const int row = lin >> 3;
      const int sc = (lin & 7) ^ (row & 7);
      gload_lds16(A + (size_t)(bm + row) * KD + k0 + sc * 8,
                  &As[buf][0][0] + lin * 8);
      gload_lds16(Bt + (size_t)(bn + row) * KD + k0 + sc * 8,
                  &Bs[buf][0][0] + lin * 8);
    }
  };

  stage(0, 0);
  for (int kt = 0; kt < KD / 64; ++kt) {
    const int cur = kt & 1;
    if (kt + 1 < KD / 64) {
      stage(cur ^ 1, (kt + 1) * 64);
      asm volatile("s_waitcnt vmcnt(8)" ::: "memory");
    } else {
      asm volatile("s_waitcnt vmcnt(0)" ::: "memory");
    }
    __builtin_amdgcn_s_barrier();

    #pragma unroll
    for (int kk = 0; kk < 2; ++kk) {
      bf16x8 aF[4], bF[4];
      #pragma unroll
      for (int m = 0; m < 4; ++m) {
        const int row = wr * 64 + m * 16 + lrow;
        const int ch = (kk * 4 + lq) ^ (row & 7);
        aF[m] = *(const bf16x8*)&As[cur][row][ch * 8];
      }
      #pragma unroll
      for (int n = 0; n < 4; ++n) {
        const int row = wc * 64 + n * 16 + lrow;
        const int ch = (kk * 4 + lq) ^ (row & 7);
        bF[n] = *(const bf16x8*)&Bs[cur][row][ch * 8];
      }
      #pragma unroll
      for (int m = 0; m < 4; ++m)
        #pragma unroll
        for (int n = 0; n < 4; ++n)
          acc[m][n] = __builtin_amdgcn_mfma_f32_16x16x32_bf16(aF[m], bF[n],
                                                              acc[m][n], 0, 0, 0);
    }
    asm volatile("s_waitcnt lgkmcnt(0)" ::: "memory");
    __builtin_amdgcn_s_barrier();
  }

  #pragma unroll
  for (int m = 0; m < 4; ++m) {
    const int ri = bm + wr * 64 + m * 16 + lq * 4;
    #pragma unroll
    for (int n = 0; n < 4; ++n) {
      const int ci = bn + wc * 64 + n * 16 + lrow;
      const f32x4 v = acc[m][n];
      if (MODE == 2) {
        #pragma unroll
        for (int r = 0; r < 4; ++r)
          outf[(size_t)(ri + r) * 1024 + ci] = v[r];
      } else {
        if (ci < 2048) {  // Q or K, frag-major per-element stores
          const int cc = ci & 1023;
          const int h = cc >> 6, d = cc & 63;
          bf16_t* dst = (ci < 1024) ? outQ : outK;
          const float sc = (ci < 1024) ? QSCALE : 1.0f;
          const int fpart = (d >> 4) * 2;
          const int lpart = ((d >> 3) & 1) * 32;
          const int epart = d & 7;
          #pragma unroll
          for (int r = 0; r < 4; ++r) {
            const int i = ri + r;
            const int b = i >> 11, q = i & 2047;
            const size_t elem = (size_t)(b * 16 + h) * 131072
                + (size_t)((q >> 6) * 8 + fpart + ((q >> 5) & 1)) * 512
                + (lpart + (q & 31)) * 8 + epart;
            dst[elem] = (bf16_t)(v[r] * sc);
          }
        } else {  // V^T frag-major, 4 consecutive j -> vector store
          const int hd = ci - 2048;
          const int h = hd >> 6, d = hd & 63;
          const int b = ri >> 11, j0 = ri & 2047;
          bf16x4 pk;
          pk[0] = (bf16_t)v[0]; pk[1] = (bf16_t)v[1];
          pk[2] = (bf16_t)v[2]; pk[3] = (bf16_t)v[3];
          const size_t elem = (size_t)(b * 16 + h) * 131072
              + (size_t)((j0 >> 6) * 8 + ((j0 & 63) >> 4) * 2 + (d >> 5)) * 512
              + ((((j0 >> 3) & 1) * 32) + (d & 31)) * 8 + (j0 & 7);
          *(bf16x4*)(outV + elem) = pk;
        }
      }
    }
  }
}

// ---------------- flash attention (LDS-free loop, 2-way KV split) ----------------
// grid: 2048 blocks x 128 thr (2 waves). Logical block G = (bid&7)*256 + bid>>3
// (XCD chunking: each XCD owns 4 bh's full strips -> K/V L2-resident).
// bh = G>>6, qs = 63-(G&63) (longest strips first). Both waves own the same
// 32 q-rows; wave w processes KV tiles jt = w, w+2, ... ; merged at the end
// via one LDS exchange. Swapped QK^T / PV as R4; Q pre-scaled by 0.125*log2e.
__global__ __launch_bounds__(128) void attn_kernel(
    const bf16_t* __restrict__ Qf, const bf16_t* __restrict__ Kf,
    const bf16_t* __restrict__ Vf, bf16_t* __restrict__ Ow) {
  const int t = threadIdx.x;
  const int lane = t & 63, w = t >> 6;
  const int l31 = lane & 31, hi = lane >> 5;
  const int G = ((blockIdx.x & 7) << 8) + (blockIdx.x >> 3);
  const int bh = G >> 6;
  const int qs = 63 - (G & 63);
  const int qg = qs * 32 + l31;               // this lane's q row
  const bf16_t* Qb = Qf + (size_t)bh * 131072 + (size_t)(qs >> 1) * 4096 + (qs & 1) * 512;
  const bf16_t* Kb = Kf + (size_t)bh * 131072;
  const bf16_t* Vb = Vf + (size_t)bh * 131072;

  // Q frags (B-operand): row=q=l31, k = ks*16 + hi*8 + e
  bf16x8 qf[4];
  #pragma unroll
  for (int ks = 0; ks < 4; ++ks)
    qf[ks] = *(const bf16x8*)(Qb + ks * 1024 + lane * 8);

  f32x16 acc0 = {}, acc1 = {};  // O^T: col=q=l31, d = 32*t + 8*(r>>2) + 4*hi + (r&3)
  float m_run = -1e30f, l_run = 0.f;
  const int nt = (qs >> 1) + 1;

  for (int jt = w; jt < nt; jt += 2) {
    const bf16_t* Kt = Kb + (size_t)jt * 4096;
    const bf16_t* Vt = Vb + (size_t)jt * 4096;

    // ---- K frags, coalesced 1KB loads ----
    bf16x8 kf0[4], kf1[4];
    #pragma unroll
    for (int ks = 0; ks < 4; ++ks) {
      kf0[ks] = *(const bf16x8*)(Kt + (ks * 2 + 0) * 512 + lane * 8);
      kf1[ks] = *(const bf16x8*)(Kt + (ks * 2 + 1) * 512 + lane * 8);
    }

    // ---- S^T = mfma(K, Q): col=q=l31, j_loc=(r&3)+8*(r>>2)+4hi ----
    f32x16 st0 = {}, st1 = {};
    #pragma unroll
    for (int ks = 0; ks < 4; ++ks) {
      st0 = __builtin_amdgcn_mfma_f32_32x32x16_bf16(kf0[ks], qf[ks], st0, 0, 0, 0);
      st1 = __builtin_amdgcn_mfma_f32_32x32x16_bf16(kf1[ks], qf[ks], st1, 0, 0, 0);
    }

    // ---- V frags issued now; latency hides under softmax ----
    bf16x8 vf0[4], vf1[4];
    #pragma unroll
    for (int tt = 0; tt < 4; ++tt) {
      vf0[tt] = *(const bf16x8*)(Vt + (tt * 2 + 0) * 512 + lane * 8);
      vf1[tt] = *(const bf16x8*)(Vt + (tt * 2 + 1) * 512 + lane * 8);
    }

    // ---- causal mask (only the diagonal tile) ----
    if (jt == nt - 1) {
      const int thr = qg - jt * 64;  // mask where j_loc > thr
      #pragma unroll
      for (int r = 0; r < 16; ++r) {
        const int jl = (r & 3) + 8 * (r >> 2) + 4 * hi;
        st0[r] = (jl > thr) ? -1e30f : st0[r];
        st1[r] = (32 + jl > thr) ? -1e30f : st1[r];
      }
    }

    // ---- row max: in-register tree + one cross-half shfl ----
    float t8[8];
    #pragma unroll
    for (int i = 0; i < 8; ++i)
      t8[i] = fmaxf(fmaxf(st0[i], st0[i + 8]), fmaxf(st1[i], st1[i + 8]));
    #pragma unroll
    for (int i = 0; i < 4; ++i) t8[i] = fmaxf(t8[i], t8[i + 4]);
    float mx = fmaxf(fmaxf(t8[0], t8[1]), fmaxf(t8[2], t8[3]));
    mx = fmaxf(mx, __shfl_xor(mx, 32, 64));
    const float m_new = fmaxf(m_run, mx);
    const float corr = exp2f(m_run - m_new);
    m_run = m_new;

    // ---- exp + row sum ----
    #pragma unroll
    for (int r = 0; r < 16; ++r) {
      st0[r] = exp2f(st0[r] - m_new);
      st1[r] = exp2f(st1[r] - m_new);
    }
    float s8[8];
    #pragma unroll
    for (int i = 0; i < 8; ++i)
      s8[i] = (st0[i] + st0[i + 8]) + (st1[i] + st1[i + 8]);
    #pragma unroll
    for (int i = 0; i < 4; ++i) s8[i] += s8[i + 4];
    float sum = (s8[0] + s8[1]) + (s8[2] + s8[3]);
    sum += __shfl_xor(sum, 32, 64);
    l_run = l_run * corr + sum;

    // ---- rescale O ----
    #pragma unroll
    for (int r = 0; r < 16; ++r) { acc0[r] *= corr; acc1[r] *= corr; }

    // ---- P -> bf16 B-operand frags via packed cross-half exchange ----
    u32 Wa[8], Wb[8], Xa[8], Xb[8];
    #pragma unroll
    for (int g = 0; g < 8; ++g) {
      Wa[g] = pkbf(st0[2 * g], st0[2 * g + 1]);
      Wb[g] = pkbf(st1[2 * g], st1[2 * g + 1]);
    }
    #pragma unroll
    for (int g = 0; g < 8; ++g) {
      Xa[g] = (u32)__shfl_xor((int)Wa[g], 32, 64);
      Xb[g] = (u32)__shfl_xor((int)Wb[g], 32, 64);
    }
    uint4 u0, u1, u2, u3;
    if (hi) {
      u0 = make_uint4(Xa[2], Xa[3], Wa[2], Wa[3]);
      u1 = make_uint4(Xa[6], Xa[7], Wa[6], Wa[7]);
      u2 = make_uint4(Xb[2], Xb[3], Wb[2], Wb[3]);
      u3 = make_uint4(Xb[6], Xb[7], Wb[6], Wb[7]);
    } else {
      u0 = make_uint4(Wa[0], Wa[1], Xa[0], Xa[1]);
      u1 = make_uint4(Wa[4], Wa[5], Xa[4], Xa[5]);
      u2 = make_uint4(Wb[0], Wb[1], Xb[0], Xb[1]);
      u3 = make_uint4(Wb[4], Wb[5], Xb[4], Xb[5]);
    }
    const bf16x8 pf0 = __builtin_bit_cast(bf16x8, u0);
    const bf16x8 pf1 = __builtin_bit_cast(bf16x8, u1);
    const bf16x8 pf2 = __builtin_bit_cast(bf16x8, u2);
    const bf16x8 pf3 = __builtin_bit_cast(bf16x8, u3);

    // ---- O^T += mfma(V, P) ----
    #pragma unroll
    for (int tt = 0; tt < 4; ++tt) {
      const bf16x8 pf = tt == 0 ? pf0 : tt == 1 ? pf1 : tt == 2 ? pf2 : pf3;
      acc0 = __builtin_amdgcn_mfma_f32_32x32x16_bf16(vf0[tt], pf, acc0, 0, 0, 0);
      acc1 = __builtin_amdgcn_mfma_f32_32x32x16_bf16(vf1[tt], pf, acc1, 0, 0, 0);
    }
  }

  // ---- cross-wave merge via LDS (wave1 -> wave0) ----
  __shared__ float mO[32][64];
  __shared__ float mML[2][64];
  if (w == 1) {
    mML[0][lane] = m_run;
    mML[1][lane] = l_run;
    #pragma unroll
    for (int r = 0; r < 16; ++r) {
      mO[r][lane] = acc0[r];
      mO[16 + r][lane] = acc1[r];
    }
  }
  __syncthreads();
  if (w == 0) {
    const float m1 = mML[0][lane], l1 = mML[1][lane];
    const float mt = fmaxf(m_run, m1);
    const float c0 = exp2f(m_run - mt), c1 = exp2f(m1 - mt);
    const float l = l_run * c0 + l1 * c1;
    const float inv = 1.0f / l;
    const int b = bh >> 4, h = bh & 15;
    bf16_t* Obase = Ow + (((size_t)(b * 2048 + qg)) << 10) + h * 64;
    #pragma unroll
    for (int g = 0; g < 4; ++g) {
      bf16x4 p0, p1;
      #pragma unroll
      for (int j = 0; j < 4; ++j) {
        p0[j] = (bf16_t)((acc0[4 * g + j] * c0 + mO[4 * g + j][lane] * c1) * inv);
        p1[j] = (bf16_t)((acc1[4 * g + j] * c0 + mO[16 + 4 * g + j][lane] * c1) * inv);
      }
      *(bf16x4*)(Obase + 8 * g + 4 * hi) = p0;
      *(bf16x4*)(Obase + 32 + 8 * g + 4 * hi) = p1;
    }
  }
}

// ---------------- orchestration ----------------
extern "C" void kernel_launch(void* const* d_in, const int* in_sizes, int n_in,
                              void* d_out, int out_size, void* d_ws, size_t ws_size,
                              hipStream_t stream) {
  const float* x   = (const float*)d_in[0];
  const float* Wq  = (const float*)d_in[1];
  const float* Wkv = (const float*)d_in[2];
  const float* Wo  = (const float*)d_in[3];
  float* out = (float*)d_out;
  char* ws = (char*)d_ws;

  const size_t MB = 1024 * 1024;
  bf16_t* Xbf   = (bf16_t*)(ws);             // [4096][1024]       8 MiB
  bf16_t* Wqkvt = (bf16_t*)(ws + 8 * MB);    // [3072][1024]       6 MiB
  bf16_t* Wot   = (bf16_t*)(ws + 14 * MB);   // [1024][1024]       2 MiB
  bf16_t* Qw    = (bf16_t*)(ws + 16 * MB);   // frag-major Q       8 MiB (pre-scaled)
  bf16_t* Kw    = (bf16_t*)(ws + 24 * MB);   // frag-major K       8 MiB
  bf16_t* Vtw   = (bf16_t*)(ws + 32 * MB);   // frag-major V^T     8 MiB
  bf16_t* Aw    = (bf16_t*)(ws + 40 * MB);   // [4096][1024]       8 MiB

  cvt_kernel<<<4096, 256, 0, stream>>>(x, Xbf);
  dim3 tb(32, 8);
  transpose_kernel<<<dim3(32, 32), tb, 0, stream>>>(Wq, Wqkvt, 1024, 1024);
  transpose_kernel<<<dim3(64, 32), tb, 0, stream>>>(Wkv, Wqkvt + 1024 * 1024, 1024, 2048);
  transpose_kernel<<<dim3(32, 32), tb, 0, stream>>>(Wo, Wot, 1024, 1024);

  gemm_kernel<1><<<dim3(24, 32), 256, 0, stream>>>(Xbf, Wqkvt, Qw, Kw, Vtw, nullptr);
  attn_kernel<<<2048, 128, 0, stream>>>(Qw, Kw, Vtw, Aw);
  gemm_kernel<2><<<dim3(8, 32), 256, 0, stream>>>(Aw, Wot, nullptr, nullptr, nullptr, out);
}

// Round 6
// 120.556 us; speedup vs baseline: 1.7569x; 1.0796x over previous
//
#include <hip/hip_runtime.h>
#include <cstdint>

// FlashAttention fused block: q/k/v proj -> causal attn -> out proj
// B=2, N=2048, DIM=1024, H=16, Dh=64. All compute bf16 MFMA + fp32 accum.
// R6: attn tile-loop latency cuts: K reg double-buffer prefetch, defer-max
// (T13), per-lane half-row l (no per-tile sum shuffle), raw v_exp_f32.

typedef __bf16 bf16_t;
typedef __bf16 bf16x8 __attribute__((ext_vector_type(8)));
typedef __bf16 bf16x4 __attribute__((ext_vector_type(4)));
typedef float  f32x4  __attribute__((ext_vector_type(4)));
typedef float  f32x16 __attribute__((ext_vector_type(16)));
typedef unsigned int u32;

#define QSCALE 0.18033688011112042f  /* 0.125 * log2(e) */

// Fragment-major layouts (per bh, 131072 elems = 2048x64):
//  K/Q: elem = bh*131072 + ((q>>6)*8 + (d>>4)*2 + ((q>>5)&1))*512
//             + (((d>>3)&1)*32 + (q&31))*8 + (d&7)
//  V^T: elem = bh*131072 + ((j>>6)*8 + ((j&63)>>4)*2 + (d>>5))*512
//             + (((j>>3)&1)*32 + (d&31))*8 + (j&7)

__device__ __forceinline__ float fast_exp2(float x) {
#if __has_builtin(__builtin_amdgcn_exp2f)
  return __builtin_amdgcn_exp2f(x);
#else
  return exp2f(x);
#endif
}

// global -> LDS direct DMA, 16B per lane. LDS dest must be uniform-base + lane*16.
__device__ __forceinline__ void gload_lds16(const void* gsrc, void* ldst) {
  __builtin_amdgcn_global_load_lds(
      (__attribute__((address_space(1))) void*)(uintptr_t)gsrc,
      (__attribute__((address_space(3))) void*)(uintptr_t)(uint32_t)(uintptr_t)ldst,
      16, 0, 0);
}

__device__ __forceinline__ u32 pkbf(float a, float b) {
  const u32 lo = (u32)__builtin_bit_cast(unsigned short, (bf16_t)a);
  const u32 hi = (u32)__builtin_bit_cast(unsigned short, (bf16_t)b);
  return (hi << 16) | lo;
}

// ---------------- prep: fp32 -> bf16 convert ----------------
__global__ __launch_bounds__(256) void cvt_kernel(const float* __restrict__ in,
                                                  bf16_t* __restrict__ out) {
  const int idx = (blockIdx.x * 256 + threadIdx.x) * 4;
  const float4 v = *(const float4*)(in + idx);
  bf16x4 o;
  o[0] = (bf16_t)v.x; o[1] = (bf16_t)v.y; o[2] = (bf16_t)v.z; o[3] = (bf16_t)v.w;
  *(bf16x4*)(out + idx) = o;
}

// ---------------- prep: W [K][Nn] fp32 -> Wt [Nn][K] bf16 ----------------
__global__ __launch_bounds__(256) void transpose_kernel(const float* __restrict__ W,
                                                        bf16_t* __restrict__ Wt,
                                                        int K, int Nn) {
  __shared__ float tile[32][33];
  const int bx = blockIdx.x, by = blockIdx.y;
  const int x = bx * 32 + threadIdx.x;
  #pragma unroll
  for (int r0 = 0; r0 < 32; r0 += 8) {
    const int r = r0 + threadIdx.y;
    tile[r][threadIdx.x] = W[(size_t)(by * 32 + r) * Nn + x];
  }
  __syncthreads();
  const int xo = by * 32 + threadIdx.x;
  #pragma unroll
  for (int r0 = 0; r0 < 32; r0 += 8) {
    const int r = r0 + threadIdx.y;
    Wt[(size_t)(bx * 32 + r) * K + xo] = (bf16_t)tile[threadIdx.x][r];
  }
}

// ---------------- GEMM: C[M][Nn] = A[M][1024] @ Bt[Nn][1024]^T ----------------
// 128x128 tile, BK=64, 4 waves (2x2 of 64x64), 16x16x32 bf16 MFMA.
// LDS chunk swizzle: physical chunk c holds logical chunk c ^ (row&7).
// 2-phase double-buffer: prefetch next K-tile, counted vmcnt(8).
// MODE 1: fused QKV. ci<1024 -> Q frag-major (scaled); <2048 -> K frag-major;
//         >=2048 -> V^T frag-major.
// MODE 2: outf = fp32 row-major [M][1024]
template <int MODE>
__global__ __launch_bounds__(256) void gemm_kernel(
    const bf16_t* __restrict__ A, const bf16_t* __restrict__ Bt,
    bf16_t* __restrict__ outQ, bf16_t* __restrict__ outK,
    bf16_t* __restrict__ outV, float* __restrict__ outf) {
  constexpr int KD = 1024;
  __shared__ bf16_t As[2][128][64];
  __shared__ bf16_t Bs[2][128][64];
  const int t = threadIdx.x;
  const int lane = t & 63, w = t >> 6;
  const int wr = w >> 1, wc = w & 1;
  const int lrow = lane & 15, lq = lane >> 4;
  const int bm = blockIdx.y * 128, bn = blockIdx.x * 128;

  f32x4 acc[4][4] = {};

  auto stage = [&](int buf, int k0) {
    #pragma unroll
    for (int i = 0; i < 4; ++i) {
      const int lin = i * 256 + t;
      const int row = lin >> 3;
      const int sc = (lin & 7) ^ (row & 7);
      gload_lds16(A + (size_t)(bm + row) * KD + k0 + sc * 8,
                  &As[buf][0][0] + lin * 8);
      gload_lds16(Bt + (size_t)(bn + row) * KD + k0 + sc * 8,
                  &Bs[buf][0][0] + lin * 8);
    }
  };

  stage(0, 0);
  for (int kt = 0; kt < KD / 64; ++kt) {
    const int cur = kt & 1;
    if (kt + 1 < KD / 64) {
      stage(cur ^ 1, (kt + 1) * 64);
      asm volatile("s_waitcnt vmcnt(8)" ::: "memory");
    } else {
      asm volatile("s_waitcnt vmcnt(0)" ::: "memory");
    }
    __builtin_amdgcn_s_barrier();

    #pragma unroll
    for (int kk = 0; kk < 2; ++kk) {
      bf16x8 aF[4], bF[4];
      #pragma unroll
      for (int m = 0; m < 4; ++m) {
        const int row = wr * 64 + m * 16 + lrow;
        const int ch = (kk * 4 + lq) ^ (row & 7);
        aF[m] = *(const bf16x8*)&As[cur][row][ch * 8];
      }
      #pragma unroll
      for (int n = 0; n < 4; ++n) {
        const int row = wc * 64 + n * 16 + lrow;
        const int ch = (kk * 4 + lq) ^ (row & 7);
        bF[n] = *(const bf16x8*)&Bs[cur][row][ch * 8];
      }
      #pragma unroll
      for (int m = 0; m < 4; ++m)
        #pragma unroll
        for (int n = 0; n < 4; ++n)
          acc[m][n] = __builtin_amdgcn_mfma_f32_16x16x32_bf16(aF[m], bF[n],
                                                              acc[m][n], 0, 0, 0);
    }
    asm volatile("s_waitcnt lgkmcnt(0)" ::: "memory");
    __builtin_amdgcn_s_barrier();
  }

  #pragma unroll
  for (int m = 0; m < 4; ++m) {
    const int ri = bm + wr * 64 + m * 16 + lq * 4;
    #pragma unroll
    for (int n = 0; n < 4; ++n) {
      const int ci = bn + wc * 64 + n * 16 + lrow;
      const f32x4 v = acc[m][n];
      if (MODE == 2) {
        #pragma unroll
        for (int r = 0; r < 4; ++r)
          outf[(size_t)(ri + r) * 1024 + ci] = v[r];
      } else {
        if (ci < 2048) {  // Q or K, frag-major per-element stores
          const int cc = ci & 1023;
          const int h = cc >> 6, d = cc & 63;
          bf16_t* dst = (ci < 1024) ? outQ : outK;
          const float sc = (ci < 1024) ? QSCALE : 1.0f;
          const int fpart = (d >> 4) * 2;
          const int lpart = ((d >> 3) & 1) * 32;
          const int epart = d & 7;
          #pragma unroll
          for (int r = 0; r < 4; ++r) {
            const int i = ri + r;
            const int b = i >> 11, q = i & 2047;
            const size_t elem = (size_t)(b * 16 + h) * 131072
                + (size_t)((q >> 6) * 8 + fpart + ((q >> 5) & 1)) * 512
                + (lpart + (q & 31)) * 8 + epart;
            dst[elem] = (bf16_t)(v[r] * sc);
          }
        } else {  // V^T frag-major, 4 consecutive j -> vector store
          const int hd = ci - 2048;
          const int h = hd >> 6, d = hd & 63;
          const int b = ri >> 11, j0 = ri & 2047;
          bf16x4 pk;
          pk[0] = (bf16_t)v[0]; pk[1] = (bf16_t)v[1];
          pk[2] = (bf16_t)v[2]; pk[3] = (bf16_t)v[3];
          const size_t elem = (size_t)(b * 16 + h) * 131072
              + (size_t)((j0 >> 6) * 8 + ((j0 & 63) >> 4) * 2 + (d >> 5)) * 512
              + ((((j0 >> 3) & 1) * 32) + (d & 31)) * 8 + (j0 & 7);
          *(bf16x4*)(outV + elem) = pk;
        }
      }
    }
  }
}

// ---------------- flash attention (LDS-free loop, 2-way KV split) ----------------
// grid: 2048 blocks x 128 thr (2 waves). Logical block G = (bid&7)*256 + bid>>3
// (XCD chunking). bh = G>>6, qs = 63-(G&63). Wave w processes KV tiles
// jt = w, w+2, ...; K reg-double-buffered (prefetch jt+2); defer-max; per-lane
// half-row l; merged across waves at the end via one LDS exchange.
__global__ __launch_bounds__(128) void attn_kernel(
    const bf16_t* __restrict__ Qf, const bf16_t* __restrict__ Kf,
    const bf16_t* __restrict__ Vf, bf16_t* __restrict__ Ow) {
  const int t = threadIdx.x;
  const int lane = t & 63, w = t >> 6;
  const int l31 = lane & 31, hi = lane >> 5;
  const int G = ((blockIdx.x & 7) << 8) + (blockIdx.x >> 3);
  const int bh = G >> 6;
  const int qs = 63 - (G & 63);
  const int qg = qs * 32 + l31;               // this lane's q row
  const bf16_t* Qb = Qf + (size_t)bh * 131072 + (size_t)(qs >> 1) * 4096 + (qs & 1) * 512;
  const bf16_t* Kb = Kf + (size_t)bh * 131072;
  const bf16_t* Vb = Vf + (size_t)bh * 131072;

  // Q frags (B-operand): row=q=l31, k = ks*16 + hi*8 + e
  bf16x8 qf[4];
  #pragma unroll
  for (int ks = 0; ks < 4; ++ks)
    qf[ks] = *(const bf16x8*)(Qb + ks * 1024 + lane * 8);

  f32x16 acc0 = {}, acc1 = {};  // O^T: col=q=l31, d = 32*t + 8*(r>>2) + 4*hi + (r&3)
  float m_run = -1e30f, l_half = 0.f;  // l_half: this lane's 32-j partial sum
  const int nt = (qs >> 1) + 1;

  auto loadK = [&](bf16x8 (&kf)[8], const bf16_t* Kt) {
    #pragma unroll
    for (int f = 0; f < 8; ++f)
      kf[f] = *(const bf16x8*)(Kt + f * 512 + lane * 8);
  };

  // one KV tile: uses kc, prefetches K(jt+2) into kn
  auto process = [&](int jt, bf16x8 (&kc)[8], bf16x8 (&kn)[8]) {
    if (jt + 2 < nt) loadK(kn, Kb + (size_t)(jt + 2) * 4096);

    // ---- S^T = mfma(K, Q): col=q=l31, j_loc=(r&3)+8*(r>>2)+4hi ----
    f32x16 st0 = {}, st1 = {};
    #pragma unroll
    for (int ks = 0; ks < 4; ++ks) {
      st0 = __builtin_amdgcn_mfma_f32_32x32x16_bf16(kc[2 * ks], qf[ks], st0, 0, 0, 0);
      st1 = __builtin_amdgcn_mfma_f32_32x32x16_bf16(kc[2 * ks + 1], qf[ks], st1, 0, 0, 0);
    }

    // ---- V frags issued now; latency hides under softmax/pack ----
    bf16x8 vf[8];
    #pragma unroll
    for (int f = 0; f < 8; ++f)
      vf[f] = *(const bf16x8*)(Vb + (size_t)jt * 4096 + f * 512 + lane * 8);

    // ---- causal mask (only the diagonal tile) ----
    if (jt == nt - 1) {
      const int thr = qg - jt * 64;  // mask where j_loc > thr
      #pragma unroll
      for (int r = 0; r < 16; ++r) {
        const int jl = (r & 3) + 8 * (r >> 2) + 4 * hi;
        st0[r] = (jl > thr) ? -1e30f : st0[r];
        st1[r] = (32 + jl > thr) ? -1e30f : st1[r];
      }
    }

    // ---- per-lane partial max over own 32 values ----
    float t8[8];
    #pragma unroll
    for (int i = 0; i < 8; ++i)
      t8[i] = fmaxf(fmaxf(st0[i], st0[i + 8]), fmaxf(st1[i], st1[i + 8]));
    #pragma unroll
    for (int i = 0; i < 4; ++i) t8[i] = fmaxf(t8[i], t8[i + 4]);
    const float pmax = fmaxf(fmaxf(t8[0], t8[1]), fmaxf(t8[2], t8[3]));

    // ---- defer-max (T13): rescale only when some row grew > threshold ----
    if (!__all(pmax <= m_run + 8.0f)) {
      const float mx = fmaxf(pmax, __shfl_xor(pmax, 32, 64));
      const float m_new = fmaxf(m_run, mx);
      const float corr = fast_exp2(m_run - m_new);
      m_run = m_new;
      l_half *= corr;
      #pragma unroll
      for (int r = 0; r < 16; ++r) { acc0[r] *= corr; acc1[r] *= corr; }
    }

    // ---- exp + per-lane partial sum (no cross-half shuffle) ----
    #pragma unroll
    for (int r = 0; r < 16; ++r) {
      st0[r] = fast_exp2(st0[r] - m_run);
      st1[r] = fast_exp2(st1[r] - m_run);
    }
    float s8[8];
    #pragma unroll
    for (int i = 0; i < 8; ++i)
      s8[i] = (st0[i] + st0[i + 8]) + (st1[i] + st1[i + 8]);
    #pragma unroll
    for (int i = 0; i < 4; ++i) s8[i] += s8[i + 4];
    l_half += (s8[0] + s8[1]) + (s8[2] + s8[3]);

    // ---- P -> bf16 B-operand frags via packed cross-half exchange ----
    u32 Wa[8], Wb[8], Xa[8], Xb[8];
    #pragma unroll
    for (int g = 0; g < 8; ++g) {
      Wa[g] = pkbf(st0[2 * g], st0[2 * g + 1]);
      Wb[g] = pkbf(st1[2 * g], st1[2 * g + 1]);
    }
    #pragma unroll
    for (int g = 0; g < 8; ++g) {
      Xa[g] = (u32)__shfl_xor((int)Wa[g], 32, 64);
      Xb[g] = (u32)__shfl_xor((int)Wb[g], 32, 64);
    }
    uint4 u0, u1, u2, u3;
    if (hi) {
      u0 = make_uint4(Xa[2], Xa[3], Wa[2], Wa[3]);
      u1 = make_uint4(Xa[6], Xa[7], Wa[6], Wa[7]);
      u2 = make_uint4(Xb[2], Xb[3], Wb[2], Wb[3]);
      u3 = make_uint4(Xb[6], Xb[7], Wb[6], Wb[7]);
    } else {
      u0 = make_uint4(Wa[0], Wa[1], Xa[0], Xa[1]);
      u1 = make_uint4(Wa[4], Wa[5], Xa[4], Xa[5]);
      u2 = make_uint4(Wb[0], Wb[1], Xb[0], Xb[1]);
      u3 = make_uint4(Wb[4], Wb[5], Xb[4], Xb[5]);
    }
    const bf16x8 pf0 = __builtin_bit_cast(bf16x8, u0);
    const bf16x8 pf1 = __builtin_bit_cast(bf16x8, u1);
    const bf16x8 pf2 = __builtin_bit_cast(bf16x8, u2);
    const bf16x8 pf3 = __builtin_bit_cast(bf16x8, u3);

    // ---- O^T += mfma(V, P) ----
    #pragma unroll
    for (int tt = 0; tt < 4; ++tt) {
      const bf16x8 pf = tt == 0 ? pf0 : tt == 1 ? pf1 : tt == 2 ? pf2 : pf3;
      acc0 = __builtin_amdgcn_mfma_f32_32x32x16_bf16(vf[2 * tt], pf, acc0, 0, 0, 0);
      acc1 = __builtin_amdgcn_mfma_f32_32x32x16_bf16(vf[2 * tt + 1], pf, acc1, 0, 0, 0);
    }
  };

  if (w < nt) {
    bf16x8 kA[8], kB[8];
    loadK(kA, Kb + (size_t)w * 4096);
    int jt = w;
    for (;;) {
      process(jt, kA, kB);
      jt += 2;
      if (jt >= nt) break;
      process(jt, kB, kA);
      jt += 2;
      if (jt >= nt) break;
    }
  }

  // ---- combine the two half-lane l partials within the wave ----
  const float l_wave = l_half + __shfl_xor(l_half, 32, 64);

  // ---- cross-wave merge via LDS (wave1 -> wave0) ----
  __shared__ float mO[32][64];
  __shared__ float mML[2][64];
  if (w == 1) {
    mML[0][lane] = m_run;
    mML[1][lane] = l_wave;
    #pragma unroll
    for (int r = 0; r < 16; ++r) {
      mO[r][lane] = acc0[r];
      mO[16 + r][lane] = acc1[r];
    }
  }
  __syncthreads();
  if (w == 0) {
    const float m1 = mML[0][lane], l1 = mML[1][lane];
    const float mt = fmaxf(m_run, m1);
    const float c0 = fast_exp2(m_run - mt), c1 = fast_exp2(m1 - mt);
    const float l = l_wave * c0 + l1 * c1;
    const float inv = 1.0f / l;
    const int b = bh >> 4, h = bh & 15;
    bf16_t* Obase = Ow + (((size_t)(b * 2048 + qg)) << 10) + h * 64;
    #pragma unroll
    for (int g = 0; g < 4; ++g) {
      bf16x4 p0, p1;
      #pragma unroll
      for (int j = 0; j < 4; ++j) {
        p0[j] = (bf16_t)((acc0[4 * g + j] * c0 + mO[4 * g + j][lane] * c1) * inv);
        p1[j] = (bf16_t)((acc1[4 * g + j] * c0 + mO[16 + 4 * g + j][lane] * c1) * inv);
      }
      *(bf16x4*)(Obase + 8 * g + 4 * hi) = p0;
      *(bf16x4*)(Obase + 32 + 8 * g + 4 * hi) = p1;
    }
  }
}

// ---------------- orchestration ----------------
extern "C" void kernel_launch(void* const* d_in, const int* in_sizes, int n_in,
                              void* d_out, int out_size, void* d_ws, size_t ws_size,
                              hipStream_t stream) {
  const float* x   = (const float*)d_in[0];
  const float* Wq  = (const float*)d_in[1];
  const float* Wkv = (const float*)d_in[2];
  const float* Wo  = (const float*)d_in[3];
  float* out = (float*)d_out;
  char* ws = (char*)d_ws;

  const size_t MB = 1024 * 1024;
  bf16_t* Xbf   = (bf16_t*)(ws);             // [4096][1024]       8 MiB
  bf16_t* Wqkvt = (bf16_t*)(ws + 8 * MB);    // [3072][1024]       6 MiB
  bf16_t* Wot   = (bf16_t*)(ws + 14 * MB);   // [1024][1024]       2 MiB
  bf16_t* Qw    = (bf16_t*)(ws + 16 * MB);   // frag-major Q       8 MiB (pre-scaled)
  bf16_t* Kw    = (bf16_t*)(ws + 24 * MB);   // frag-major K       8 MiB
  bf16_t* Vtw   = (bf16_t*)(ws + 32 * MB);   // frag-major V^T     8 MiB
  bf16_t* Aw    = (bf16_t*)(ws + 40 * MB);   // [4096][1024]       8 MiB

  cvt_kernel<<<4096, 256, 0, stream>>>(x, Xbf);
  dim3 tb(32, 8);
  transpose_kernel<<<dim3(32, 32), tb, 0, stream>>>(Wq, Wqkvt, 1024, 1024);
  transpose_kernel<<<dim3(64, 32), tb, 0, stream>>>(Wkv, Wqkvt + 1024 * 1024, 1024, 2048);
  transpose_kernel<<<dim3(32, 32), tb, 0, stream>>>(Wo, Wot, 1024, 1024);

  gemm_kernel<1><<<dim3(24, 32), 256, 0, stream>>>(Xbf, Wqkvt, Qw, Kw, Vtw, nullptr);
  attn_kernel<<<2048, 128, 0, stream>>>(Qw, Kw, Vtw, Aw);
  gemm_kernel<2><<<dim3(8, 32), 256, 0, stream>>>(Aw, Wot, nullptr, nullptr, nullptr, out);
}